// Round 8
// baseline (442.703 us; speedup 1.0000x reference)
//
#include <hip/hip_runtime.h>

#define TT 2048
#define DD 1024
#define HH 16
#define DH 64
#define QKV_N 3072
#define QKW 2048  // qk buffer width (Q cols 0..1023, K cols 1024..2047)
#define NBLK 512  // fused grid: 2 blocks/CU x 256 CU, co-residency by resources

typedef __attribute__((ext_vector_type(8))) short bf16x8;
typedef __attribute__((ext_vector_type(4))) short short4v;
typedef __attribute__((ext_vector_type(4))) float f32x4;

__device__ inline short f2bf(float f) {
    union { float f; unsigned u; } v; v.f = f;
    unsigned r = v.u + 0x7fff + ((v.u >> 16) & 1);  // RNE
    return (short)(r >> 16);
}

__device__ inline f32x4 mfma16(bf16x8 a, bf16x8 b, f32x4 c) {
    return __builtin_amdgcn_mfma_f32_16x16x32_bf16(a, b, c, 0, 0, 0);
}

__device__ __forceinline__ void gload16(const void* g, void* l) {
    __builtin_amdgcn_global_load_lds(
        (const __attribute__((address_space(1))) unsigned int*)g,
        (__attribute__((address_space(3))) unsigned int*)l, 16, 0, 0);
}

// Device-scope global barrier (graph-capturable regular launch; all NBLK
// blocks co-resident by resource arithmetic). Release on arrival makes this
// phase's writes visible at agent scope; acquire on the spin invalidates
// stale L1/L2 before the next phase reads (G16, cross-XCD).
// Timeout bail (~25ms) turns a co-residency failure into a wrong-answer
// bench fail instead of a container-killing hang.
__device__ __forceinline__ void gbar(int* cnt, int* flag, int target) {
    __syncthreads();
    if (threadIdx.x == 0) {
        int t = __hip_atomic_fetch_add(cnt, 1, __ATOMIC_ACQ_REL, __HIP_MEMORY_SCOPE_AGENT);
        if (t == NBLK - 1) {
            __hip_atomic_store(cnt, 0, __ATOMIC_RELAXED, __HIP_MEMORY_SCOPE_AGENT);
            __hip_atomic_fetch_add(flag, 1, __ATOMIC_RELEASE, __HIP_MEMORY_SCOPE_AGENT);
        } else {
            long long t0 = clock64();
            while (__hip_atomic_load(flag, __ATOMIC_ACQUIRE, __HIP_MEMORY_SCOPE_AGENT) < target) {
                if (clock64() - t0 > 60000000LL) break;  // ~25ms bail
                __builtin_amdgcn_s_sleep(2);
            }
        }
    }
    __syncthreads();
}

// Shared-memory union: phases sequential, buffers alias. Max 50176 B ->
// 2 blocks/CU by LDS (<=80KB each); launch_bounds(256,2) caps VGPR<=256.
union SharedMem {
    struct { short As[2][2][64 * 32]; short Bs[2][2][128 * 32]; } g;  // 48 KB
    struct { short Qh[2][64 * 32]; short Kh[2][2][64 * 32];
             short Vh[2][2][64 * 32]; short Ss[64 * 72]; } a;         // 49 KB
    struct { float tile[64][65]; int scanbuf[2561]; } p;              // 26 KB
};

__device__ void transpose_tile(const float* __restrict__ in, short* __restrict__ out,
                               int R, int C, int r0, int c0, float (*tile)[65]) {
    int tid = threadIdx.x;
#pragma unroll
    for (int p = 0; p < 4; ++p) {
        int ch = tid + p * 256;
        int r = ch >> 4, c4 = (ch & 15) * 4;
        float4 v = *(const float4*)&in[(size_t)(r0 + r) * C + c0 + c4];
        tile[r][c4] = v.x; tile[r][c4 + 1] = v.y; tile[r][c4 + 2] = v.z; tile[r][c4 + 3] = v.w;
    }
    __syncthreads();
#pragma unroll
    for (int p = 0; p < 2; ++p) {
        int ch = tid + p * 256;
        int c = ch >> 3, r8 = (ch & 7) * 8;
        short tmp[8];
#pragma unroll
        for (int i = 0; i < 8; ++i) tmp[i] = f2bf(tile[r8 + i][c]);
        *(float4*)&out[(size_t)(c0 + c) * R + r0 + r8] = *(float4*)tmp;
    }
}

// ---------------------------------------------------------------------------
// Fused kernel: prep -> qkv -> attn -> out-proj with software grid barriers.
// grid NBLK x 256.
// ---------------------------------------------------------------------------
__global__ __launch_bounds__(256, 2) void fused_kernel(
    const float* __restrict__ x, const float* __restrict__ w_qkv,
    const float* __restrict__ w_out, const float* __restrict__ state,
    const int* __restrict__ done, const float* __restrict__ b_qkv,
    const float* __restrict__ b_out,
    short* __restrict__ xo,    // x_bf (phases 0-1), then outb (phases 2-3)
    short* __restrict__ wqT, short* __restrict__ woT, short* __restrict__ stT,
    short* __restrict__ qk, short* __restrict__ vt,
    float* __restrict__ nsout, float* __restrict__ x_out,
    int* __restrict__ seg, int* __restrict__ totalp, int* __restrict__ aux,
    int* __restrict__ bar) {
    __shared__ __align__(16) SharedMem sh;
    __shared__ int anyf;
    int* cnt = bar;
    int* flag = bar + 4;

    int bid = blockIdx.x;
    int tid = threadIdx.x;
    int wave = tid >> 6, lane = tid & 63;
    int quad = lane >> 4, l15 = lane & 15;

    // ===================== phase 0: prep (2129 virtual blocks) ==============
    for (int vb = bid; vb < 2129; vb += NBLK) {
        __syncthreads();
        int b = vb;
        if (b < 1024) {
            int i = (b * 256 + tid) * 8;
            float4 a = *(const float4*)&x[i];
            float4 c = *(const float4*)&x[i + 4];
            short tmp[8] = {f2bf(a.x), f2bf(a.y), f2bf(a.z), f2bf(a.w),
                            f2bf(c.x), f2bf(c.y), f2bf(c.z), f2bf(c.w)};
            *(float4*)&xo[i] = *(float4*)tmp;
        } else if (b < 1792) {
            int bb = b - 1024;
            transpose_tile(w_qkv, wqT, DD, QKV_N, (bb & 15) * 64, (bb >> 4) * 64, sh.p.tile);
        } else if (b < 2048) {
            int bb = b - 1792;
            transpose_tile(w_out, woT, DD, DD, (bb & 15) * 64, (bb >> 4) * 64, sh.p.tile);
        } else if (b < 2064) {
            int h = b - 2048;
            transpose_tile(state + (size_t)h * 4096, stT + (size_t)h * 4096, DH, DH, 0, 0, sh.p.tile);
        } else if (b < 2128) {
            if (tid == 0) anyf = 0;
            __syncthreads();
            int acc = 0;
#pragma unroll
            for (int i = 0; i < 8; ++i) acc |= done[tid * 8 + i];
            if (acc) anyf = 1;
            __syncthreads();
            int f = ((b - 2064) * 256 + tid) * 4;
            float4 v = anyf ? make_float4(0.f, 0.f, 0.f, 0.f) : *(const float4*)&state[f];
            *(float4*)&nsout[f] = v;
        } else {
            int* segl = sh.p.scanbuf;
            int* part = sh.p.scanbuf + 2048;
            int* excl = sh.p.scanbuf + 2304;
            int base = tid * 8;
            int local[8];
            int run = 0;
#pragma unroll
            for (int i = 0; i < 8; ++i) { run += (done[base + i] != 0) ? 1 : 0; local[i] = run; }
            part[tid] = run;
            __syncthreads();
            if (tid < 64) {
                int p4[4];
#pragma unroll
                for (int i = 0; i < 4; ++i) p4[i] = part[tid * 4 + i];
                int s = p4[0] + p4[1] + p4[2] + p4[3];
                int v = s;
#pragma unroll
                for (int off = 1; off < 64; off <<= 1) {
                    int u = __shfl_up(v, off);
                    if (tid >= off) v += u;
                }
                int ex = v - s;
#pragma unroll
                for (int i = 0; i < 4; ++i) { excl[tid * 4 + i] = ex; ex += p4[i]; }
                if (tid == 63) { totalp[0] = v; sh.p.scanbuf[2560] = v; }
            }
            __syncthreads();
            int off = excl[tid];
#pragma unroll
            for (int i = 0; i < 8; ++i) {
                int sv = off + local[i];
                seg[base + i] = sv;
                segl[base + i] = sv;
            }
            __syncthreads();
            if (tid < 33) {
                int target = (tid < 32) ? segl[tid * 64] : sh.p.scanbuf[2560];
                int lo = 0, hi = 2047;
                while (lo < hi) { int mid = (lo + hi) >> 1; if (segl[mid] >= target) hi = mid; else lo = mid + 1; }
                aux[tid] = lo >> 6;
            }
        }
    }
    gbar(cnt, flag, 1);

    // ===================== phase 1: QKV GEMM (768 virtual blocks) ===========
    for (int vb = bid; vb < 768; vb += NBLK) {
        __syncthreads();
        const int K = DD;
        int m0 = (vb & 31) * 64, n0 = (vb >> 5) * 128;
        int wr = (wave >> 1) * 32, wc = (wave & 1) * 64;
        int srow = wave * 16 + (lane >> 2);
        int scol = (lane & 3) * 8;
        const short* Ag = xo + (size_t)(m0 + srow) * K + scol;
        const short* Bg = wqT + (size_t)(n0 + srow) * K + scol;

#pragma unroll
        for (int ks = 0; ks < 2; ++ks) {
            gload16(Ag + ks * 32, &sh.g.As[0][ks][(wave * 16) * 32]);
            gload16(Bg + ks * 32, &sh.g.Bs[0][ks][(wave * 16) * 32]);
            gload16(Bg + (size_t)64 * K + ks * 32, &sh.g.Bs[0][ks][(64 + wave * 16) * 32]);
        }
        __syncthreads();

        f32x4 acc[2][4] = {};
        int cur = 0;
        for (int k0 = 0; k0 < K; k0 += 64, cur ^= 1) {
            if (k0 + 64 < K) {
#pragma unroll
                for (int ks = 0; ks < 2; ++ks) {
                    gload16(Ag + k0 + 64 + ks * 32, &sh.g.As[cur ^ 1][ks][(wave * 16) * 32]);
                    gload16(Bg + k0 + 64 + ks * 32, &sh.g.Bs[cur ^ 1][ks][(wave * 16) * 32]);
                    gload16(Bg + (size_t)64 * K + k0 + 64 + ks * 32,
                            &sh.g.Bs[cur ^ 1][ks][(64 + wave * 16) * 32]);
                }
            }
#pragma unroll
            for (int ks = 0; ks < 2; ++ks) {
                bf16x8 af[2], bfr[4];
#pragma unroll
                for (int i = 0; i < 2; ++i)
                    af[i]  = *(const bf16x8*)&sh.g.As[cur][ks][(wr + i * 16 + l15) * 32 + quad * 8];
#pragma unroll
                for (int j = 0; j < 4; ++j)
                    bfr[j] = *(const bf16x8*)&sh.g.Bs[cur][ks][(wc + j * 16 + l15) * 32 + quad * 8];
#pragma unroll
                for (int i = 0; i < 2; ++i)
#pragma unroll
                    for (int j = 0; j < 4; ++j)
                        acc[i][j] = mfma16(af[i], bfr[j], acc[i][j]);
            }
            __syncthreads();
        }

        if (n0 < 2048) {
#pragma unroll
            for (int i = 0; i < 2; ++i)
#pragma unroll
                for (int j = 0; j < 4; ++j)
#pragma unroll
                    for (int r = 0; r < 4; ++r) {
                        int row = m0 + wr + i * 16 + quad * 4 + r;
                        int col = n0 + wc + j * 16 + l15;
                        qk[(size_t)row * QKW + col] = f2bf(acc[i][j][r] + b_qkv[col]);
                    }
        } else {
#pragma unroll
            for (int j = 0; j < 4; ++j) {
                int col = n0 + wc + j * 16 + l15;
                float bv = b_qkv[col];
                int eg = col - 2048;
                int hh = eg >> 6, e = eg & 63;
#pragma unroll
                for (int i = 0; i < 2; ++i) {
                    int tb = m0 + wr + i * 16 + quad * 4;
                    short4v pk;
#pragma unroll
                    for (int r = 0; r < 4; ++r) pk[r] = f2bf(acc[i][j][r] + bv);
                    *(short4v*)&vt[(size_t)hh * (DH * TT) + (size_t)e * TT + tb] = pk;
                }
            }
        }
    }
    gbar(cnt, flag, 2);

    // ===================== phase 2: attention (1024 virtual blocks) =========
    for (int vb = bid; vb < 1024; vb += NBLK) {
        __syncthreads();
        int z = vb >> 9;
        int rem = vb & 511;
        int h = rem & 15, tt = rem >> 4;
        int t0 = tt * 64;
        int myt = wave * 16;
        const short* vbase = vt + (size_t)h * (DH * TT);

        if (z == 1) {
            if (tt >= aux[32]) {
                int total = totalp[0];
                int myd = wave * 16;
                short* K0 = sh.a.Kh[0][0];
                short* K1 = sh.a.Kh[0][1];
                bool keep = (seg[t0 + lane] == total);
                const short* src = qk + (size_t)(t0 + lane) * QKW + 1024 + h * DH + myd;
                union { float4 f; short s[8]; } u0, u1;
                u0.f = keep ? *(const float4*)src : make_float4(0.f, 0.f, 0.f, 0.f);
                u1.f = keep ? *(const float4*)(src + 8) : make_float4(0.f, 0.f, 0.f, 0.f);
                short* dst = (lane < 32) ? &K0[lane] : &K1[lane - 32];
#pragma unroll
                for (int i = 0; i < 8; ++i) {
                    dst[(myd + i) * 32] = u0.s[i];
                    dst[(myd + 8 + i) * 32] = u1.s[i];
                }
                bf16x8 a0 = *(const bf16x8*)&K0[(myd + l15) * 32 + quad * 8];
                bf16x8 a1 = *(const bf16x8*)&K1[(myd + l15) * 32 + quad * 8];
                f32x4 acc2[4] = {};
#pragma unroll
                for (int j = 0; j < 4; ++j) {
                    const short* vrow = vbase + (size_t)(j * 16 + l15) * TT + t0 + quad * 8;
                    bf16x8 b0 = *(const bf16x8*)vrow;
                    bf16x8 b1 = *(const bf16x8*)(vrow + 32);
                    acc2[j] = mfma16(a0, b0, acc2[j]);
                    acc2[j] = mfma16(a1, b1, acc2[j]);
                }
                float* oh = nsout + (size_t)h * 4096;
#pragma unroll
                for (int j = 0; j < 4; ++j)
#pragma unroll
                    for (int r = 0; r < 4; ++r)
                        atomicAdd(&oh[(myd + quad * 4 + r) * DH + j * 16 + l15], acc2[j][r]);
            }
            continue;
        }

        int st0 = aux[tt];
        int sr = lane >> 2;
        int ch = lane & 3;
        const short* kg = qk + 1024 + h * DH;

        {
#pragma unroll
            for (int h2 = 0; h2 < 2; ++h2)
                gload16(qk + (size_t)(t0 + myt + sr) * QKW + h * DH + h2 * 32 + ch * 8,
                        &sh.a.Qh[h2][myt * 32]);
            int s0 = st0 * 64;
            gload16(kg + (size_t)(s0 + myt + sr) * QKW + ch * 8,        &sh.a.Kh[0][0][myt * 32]);
            gload16(kg + (size_t)(s0 + myt + sr) * QKW + 32 + ch * 8,   &sh.a.Kh[0][1][myt * 32]);
            gload16(vbase + (size_t)(myt + sr) * TT + s0 + ch * 8,      &sh.a.Vh[0][0][myt * 32]);
            gload16(vbase + (size_t)(myt + sr) * TT + s0 + 32 + ch * 8, &sh.a.Vh[0][1][myt * 32]);
        }
        __syncthreads();

        bf16x8 af[2];
#pragma unroll
        for (int h2 = 0; h2 < 2; ++h2)
            af[h2] = *(const bf16x8*)&sh.a.Qh[h2][(myt + l15) * 32 + quad * 8];

        int t_val = t0 + myt + l15;
        int seg_lane = seg[t_val];

        f32x4 acc2[4] = {};
        if (seg[t0] == 0) {
            const short* sb = stT + (size_t)h * 4096;
#pragma unroll
            for (int j = 0; j < 4; ++j)
#pragma unroll
                for (int h2 = 0; h2 < 2; ++h2) {
                    bf16x8 a = *(const bf16x8*)(sb + (j * 16 + l15) * 64 + h2 * 32 + quad * 8);
                    acc2[j] = mfma16(a, af[h2], acc2[j]);
                }
            if (seg_lane != 0) {
#pragma unroll
                for (int j = 0; j < 4; ++j)
#pragma unroll
                    for (int r = 0; r < 4; ++r) acc2[j][r] = 0.f;
            }
        }

        int p = 0;
        for (int st = st0; st <= tt; ++st, p ^= 1) {
            if (st != st0) __syncthreads();
            if (st + 1 <= tt) {
                int s1 = (st + 1) * 64;
                gload16(kg + (size_t)(s1 + myt + sr) * QKW + ch * 8,        &sh.a.Kh[p ^ 1][0][myt * 32]);
                gload16(kg + (size_t)(s1 + myt + sr) * QKW + 32 + ch * 8,   &sh.a.Kh[p ^ 1][1][myt * 32]);
                gload16(vbase + (size_t)(myt + sr) * TT + s1 + ch * 8,      &sh.a.Vh[p ^ 1][0][myt * 32]);
                gload16(vbase + (size_t)(myt + sr) * TT + s1 + 32 + ch * 8, &sh.a.Vh[p ^ 1][1][myt * 32]);
            }
            int s0 = st * 64;

            f32x4 sacc[4] = {};
#pragma unroll
            for (int j = 0; j < 4; ++j)
#pragma unroll
                for (int h2 = 0; h2 < 2; ++h2) {
                    bf16x8 kb = *(const bf16x8*)&sh.a.Kh[p][h2][(j * 16 + l15) * 32 + quad * 8];
                    sacc[j] = mfma16(kb, af[h2], sacc[j]);
                }
            int4 seg4[4];
#pragma unroll
            for (int j = 0; j < 4; ++j)
                seg4[j] = *(const int4*)&seg[s0 + j * 16 + quad * 4];
#pragma unroll
            for (int j = 0; j < 4; ++j) {
                short4v pk;
#pragma unroll
                for (int r = 0; r < 4; ++r) {
                    int s_val = s0 + j * 16 + quad * 4 + r;
                    int sv = (r == 0) ? seg4[j].x : (r == 1) ? seg4[j].y : (r == 2) ? seg4[j].z : seg4[j].w;
                    bool ok = (sv == seg_lane) && (s_val <= t_val);
                    pk[r] = ok ? f2bf(sacc[j][r]) : (short)0;
                }
                *(short4v*)&sh.a.Ss[(myt + l15) * 72 + j * 16 + quad * 4] = pk;
            }
            bf16x8 sf[2];
#pragma unroll
            for (int h2 = 0; h2 < 2; ++h2)
                sf[h2] = *(const bf16x8*)&sh.a.Ss[(myt + l15) * 72 + h2 * 32 + quad * 8];
#pragma unroll
            for (int j = 0; j < 4; ++j)
#pragma unroll
                for (int h2 = 0; h2 < 2; ++h2) {
                    bf16x8 vb2 = *(const bf16x8*)&sh.a.Vh[p][h2][(j * 16 + l15) * 32 + quad * 8];
                    acc2[j] = mfma16(vb2, sf[h2], acc2[j]);
                }
        }

#pragma unroll
        for (int j = 0; j < 4; ++j) {
            short4v pk;
#pragma unroll
            for (int r = 0; r < 4; ++r) pk[r] = f2bf(acc2[j][r]);
            *(short4v*)&xo[(size_t)t_val * DD + h * DH + j * 16 + quad * 4] = pk;
        }
    }
    gbar(cnt, flag, 3);

    // ===================== phase 3: out-proj GEMM (256 virtual blocks) ======
    if (bid < 256) {
        const int K = DD, N = DD;
        int m0 = (bid & 31) * 64, n0 = (bid >> 5) * 128;
        int wr = (wave >> 1) * 32, wc = (wave & 1) * 64;
        int srow = wave * 16 + (lane >> 2);
        int scol = (lane & 3) * 8;
        const short* Ag = xo + (size_t)(m0 + srow) * K + scol;
        const short* Bg = woT + (size_t)(n0 + srow) * K + scol;

#pragma unroll
        for (int ks = 0; ks < 2; ++ks) {
            gload16(Ag + ks * 32, &sh.g.As[0][ks][(wave * 16) * 32]);
            gload16(Bg + ks * 32, &sh.g.Bs[0][ks][(wave * 16) * 32]);
            gload16(Bg + (size_t)64 * K + ks * 32, &sh.g.Bs[0][ks][(64 + wave * 16) * 32]);
        }
        __syncthreads();

        f32x4 acc[2][4] = {};
        int cur = 0;
        for (int k0 = 0; k0 < K; k0 += 64, cur ^= 1) {
            if (k0 + 64 < K) {
#pragma unroll
                for (int ks = 0; ks < 2; ++ks) {
                    gload16(Ag + k0 + 64 + ks * 32, &sh.g.As[cur ^ 1][ks][(wave * 16) * 32]);
                    gload16(Bg + k0 + 64 + ks * 32, &sh.g.Bs[cur ^ 1][ks][(wave * 16) * 32]);
                    gload16(Bg + (size_t)64 * K + k0 + 64 + ks * 32,
                            &sh.g.Bs[cur ^ 1][ks][(64 + wave * 16) * 32]);
                }
            }
#pragma unroll
            for (int ks = 0; ks < 2; ++ks) {
                bf16x8 af2[2], bfr[4];
#pragma unroll
                for (int i = 0; i < 2; ++i)
                    af2[i] = *(const bf16x8*)&sh.g.As[cur][ks][(wr + i * 16 + l15) * 32 + quad * 8];
#pragma unroll
                for (int j = 0; j < 4; ++j)
                    bfr[j] = *(const bf16x8*)&sh.g.Bs[cur][ks][(wc + j * 16 + l15) * 32 + quad * 8];
#pragma unroll
                for (int i = 0; i < 2; ++i)
#pragma unroll
                    for (int j = 0; j < 4; ++j)
                        acc[i][j] = mfma16(af2[i], bfr[j], acc[i][j]);
            }
            __syncthreads();
        }

#pragma unroll
        for (int i = 0; i < 2; ++i)
#pragma unroll
            for (int j = 0; j < 4; ++j) {
                int col = n0 + wc + j * 16 + l15;
                float bv = b_out[col];
#pragma unroll
                for (int r = 0; r < 4; ++r) {
                    int row = m0 + wr + i * 16 + quad * 4 + r;
                    x_out[(size_t)row * N + col] = acc[i][j][r] + bv;
                }
            }
    }
}

// ---------------------------------------------------------------------------
// Host launcher — memset barrier words + single regular dispatch.
// ---------------------------------------------------------------------------
extern "C" void kernel_launch(void* const* d_in, const int* in_sizes, int n_in,
                              void* d_out, int out_size, void* d_ws, size_t ws_size,
                              hipStream_t stream) {
    const float* state = (const float*)d_in[0];
    const float* x_in  = (const float*)d_in[1];
    const int*   done  = (const int*)d_in[2];
    const float* w_qkv = (const float*)d_in[3];
    const float* b_qkv = (const float*)d_in[4];
    const float* w_out = (const float*)d_in[5];
    const float* b_out = (const float*)d_in[6];

    char* ws = (char*)d_ws;
    int*   seg    = (int*)ws;                         // 8 KB
    int*   totalp = (int*)(ws + 8192);
    int*   aux    = (int*)(ws + 8256);                // 33 ints (ends 8388)
    int*   bar    = (int*)(ws + 8400);                // 8 ints barrier state
    short* wqT    = (short*)(ws + 8448);              // 6 MB   [3072][1024]
    short* woT    = (short*)(ws + 6299904);           // 2 MB   [1024][1024]
    short* stT    = (short*)(ws + 8397056);           // 128 KB [h][e][d]
    short* qk     = (short*)(ws + 8528128);           // 8 MB   [T][2048] (Q|K)
    short* vt     = (short*)(ws + 16916736);          // 4 MB   [h][e][T]
    short* xo     = (short*)(ws + 21111040);          // 4 MB   x_bf then outb

    float* nsout = (float*)d_out;
    float* x_out = (float*)d_out + HH * DH * DH;

    hipMemsetAsync(bar, 0, 32, stream);

    fused_kernel<<<NBLK, 256, 0, stream>>>(
        x_in, w_qkv, w_out, state, done, b_qkv, b_out,
        xo, wqT, woT, stT, qk, vt, nsout, x_out,
        seg, totalp, aux, bar);
}

// Round 9
// 329.101 us; speedup vs baseline: 1.3452x; 1.3452x over previous
//
#include <hip/hip_runtime.h>

#define TT 2048
#define DD 1024
#define HH 16
#define DH 64
#define QKV_N 3072
#define QKW 2048  // qk buffer width (Q cols 0..1023, K cols 1024..2047)
#define NBLK 512  // fused grid: 2 blocks/CU x 256 CU, co-residency by resources

typedef __attribute__((ext_vector_type(8))) short bf16x8;
typedef __attribute__((ext_vector_type(4))) short short4v;
typedef __attribute__((ext_vector_type(4))) float f32x4;

__device__ inline short f2bf(float f) {
    union { float f; unsigned u; } v; v.f = f;
    unsigned r = v.u + 0x7fff + ((v.u >> 16) & 1);  // RNE
    return (short)(r >> 16);
}

__device__ inline f32x4 mfma16(bf16x8 a, bf16x8 b, f32x4 c) {
    return __builtin_amdgcn_mfma_f32_16x16x32_bf16(a, b, c, 0, 0, 0);
}

__device__ __forceinline__ void gload16(const void* g, void* l) {
    __builtin_amdgcn_global_load_lds(
        (const __attribute__((address_space(1))) unsigned int*)g,
        (__attribute__((address_space(3))) unsigned int*)l, 16, 0, 0);
}

// Device-scope global barrier, CACHE-BENIGN spin:
//  - one release fence per block before arrival (publishes phase writes);
//  - RELAXED spin loads (no per-iteration buffer_inv — R8's 100us/barrier
//    cost was the ACQUIRE-per-spin invalidations shredding the caches of
//    the still-working blocks);
//  - one acquire fence by ALL threads after the barrier.
// Timeout bail (~25ms) turns a co-residency failure into a wrong answer,
// not a hang.
__device__ __forceinline__ void gbar(int* cnt, int* flag, int target) {
    __syncthreads();
    if (threadIdx.x == 0) {
        __builtin_amdgcn_fence(__ATOMIC_RELEASE, "agent");
        int t = __hip_atomic_fetch_add(cnt, 1, __ATOMIC_RELAXED, __HIP_MEMORY_SCOPE_AGENT);
        if (t == NBLK - 1) {
            __hip_atomic_store(cnt, 0, __ATOMIC_RELAXED, __HIP_MEMORY_SCOPE_AGENT);
            __hip_atomic_fetch_add(flag, 1, __ATOMIC_RELAXED, __HIP_MEMORY_SCOPE_AGENT);
        } else {
            long long t0 = clock64();
            while (__hip_atomic_load(flag, __ATOMIC_RELAXED, __HIP_MEMORY_SCOPE_AGENT) < target) {
                __builtin_amdgcn_s_sleep(16);
                if (clock64() - t0 > 60000000LL) break;  // ~25ms bail
            }
        }
    }
    __syncthreads();
    __builtin_amdgcn_fence(__ATOMIC_ACQUIRE, "agent");
}

// Shared-memory union: phases sequential, buffers alias. Max 50176 B ->
// 2 blocks/CU by LDS (<=80KB each); launch_bounds(256,2) caps VGPR<=256.
union SharedMem {
    struct { short As[2][2][64 * 32]; short Bs[2][2][128 * 32]; } g;  // 48 KB
    struct { short Qh[2][64 * 32]; short Kh[2][2][64 * 32];
             short Vh[2][2][64 * 32]; short Ss[64 * 72]; } a;         // 49 KB
    struct { float tile[64][65]; int scanbuf[2561]; } p;              // 26 KB
};

__device__ void transpose_tile(const float* __restrict__ in, short* __restrict__ out,
                               int R, int C, int r0, int c0, float (*tile)[65]) {
    int tid = threadIdx.x;
#pragma unroll
    for (int p = 0; p < 4; ++p) {
        int ch = tid + p * 256;
        int r = ch >> 4, c4 = (ch & 15) * 4;
        float4 v = *(const float4*)&in[(size_t)(r0 + r) * C + c0 + c4];
        tile[r][c4] = v.x; tile[r][c4 + 1] = v.y; tile[r][c4 + 2] = v.z; tile[r][c4 + 3] = v.w;
    }
    __syncthreads();
#pragma unroll
    for (int p = 0; p < 2; ++p) {
        int ch = tid + p * 256;
        int c = ch >> 3, r8 = (ch & 7) * 8;
        short tmp[8];
#pragma unroll
        for (int i = 0; i < 8; ++i) tmp[i] = f2bf(tile[r8 + i][c]);
        *(float4*)&out[(size_t)(c0 + c) * R + r0 + r8] = *(float4*)tmp;
    }
}

// ---------------------------------------------------------------------------
// Fused kernel: prep -> qkv -> attn -> out-proj with software grid barriers.
// grid NBLK x 256.
// ---------------------------------------------------------------------------
__global__ __launch_bounds__(256, 2) void fused_kernel(
    const float* __restrict__ x, const float* __restrict__ w_qkv,
    const float* __restrict__ w_out, const float* __restrict__ state,
    const int* __restrict__ done, const float* __restrict__ b_qkv,
    const float* __restrict__ b_out,
    short* __restrict__ xo,    // x_bf (phases 0-1), then outb (phases 2-3)
    short* __restrict__ wqT, short* __restrict__ woT, short* __restrict__ stT,
    short* __restrict__ qk, short* __restrict__ vt,
    float* __restrict__ nsout, float* __restrict__ x_out,
    int* __restrict__ seg, int* __restrict__ totalp, int* __restrict__ aux,
    int* __restrict__ bar) {
    __shared__ __align__(16) SharedMem sh;
    __shared__ int anyf;
    int* cnt = bar;
    int* flag = bar + 4;

    int bid = blockIdx.x;
    int tid = threadIdx.x;
    int wave = tid >> 6, lane = tid & 63;
    int quad = lane >> 4, l15 = lane & 15;

    // ===================== phase 0: prep (2129 virtual blocks) ==============
    for (int vb = bid; vb < 2129; vb += NBLK) {
        __syncthreads();
        int b = vb;
        if (b < 1024) {
            int i = (b * 256 + tid) * 8;
            float4 a = *(const float4*)&x[i];
            float4 c = *(const float4*)&x[i + 4];
            short tmp[8] = {f2bf(a.x), f2bf(a.y), f2bf(a.z), f2bf(a.w),
                            f2bf(c.x), f2bf(c.y), f2bf(c.z), f2bf(c.w)};
            *(float4*)&xo[i] = *(float4*)tmp;
        } else if (b < 1792) {
            int bb = b - 1024;
            transpose_tile(w_qkv, wqT, DD, QKV_N, (bb & 15) * 64, (bb >> 4) * 64, sh.p.tile);
        } else if (b < 2048) {
            int bb = b - 1792;
            transpose_tile(w_out, woT, DD, DD, (bb & 15) * 64, (bb >> 4) * 64, sh.p.tile);
        } else if (b < 2064) {
            int h = b - 2048;
            transpose_tile(state + (size_t)h * 4096, stT + (size_t)h * 4096, DH, DH, 0, 0, sh.p.tile);
        } else if (b < 2128) {
            if (tid == 0) anyf = 0;
            __syncthreads();
            int acc = 0;
#pragma unroll
            for (int i = 0; i < 8; ++i) acc |= done[tid * 8 + i];
            if (acc) anyf = 1;
            __syncthreads();
            int f = ((b - 2064) * 256 + tid) * 4;
            float4 v = anyf ? make_float4(0.f, 0.f, 0.f, 0.f) : *(const float4*)&state[f];
            *(float4*)&nsout[f] = v;
        } else {
            int* segl = sh.p.scanbuf;
            int* part = sh.p.scanbuf + 2048;
            int* excl = sh.p.scanbuf + 2304;
            int base = tid * 8;
            int local[8];
            int run = 0;
#pragma unroll
            for (int i = 0; i < 8; ++i) { run += (done[base + i] != 0) ? 1 : 0; local[i] = run; }
            part[tid] = run;
            __syncthreads();
            if (tid < 64) {
                int p4[4];
#pragma unroll
                for (int i = 0; i < 4; ++i) p4[i] = part[tid * 4 + i];
                int s = p4[0] + p4[1] + p4[2] + p4[3];
                int v = s;
#pragma unroll
                for (int off = 1; off < 64; off <<= 1) {
                    int u = __shfl_up(v, off);
                    if (tid >= off) v += u;
                }
                int ex = v - s;
#pragma unroll
                for (int i = 0; i < 4; ++i) { excl[tid * 4 + i] = ex; ex += p4[i]; }
                if (tid == 63) { totalp[0] = v; sh.p.scanbuf[2560] = v; }
            }
            __syncthreads();
            int off = excl[tid];
#pragma unroll
            for (int i = 0; i < 8; ++i) {
                int sv = off + local[i];
                seg[base + i] = sv;
                segl[base + i] = sv;
            }
            __syncthreads();
            if (tid < 33) {
                int target = (tid < 32) ? segl[tid * 64] : sh.p.scanbuf[2560];
                int lo = 0, hi = 2047;
                while (lo < hi) { int mid = (lo + hi) >> 1; if (segl[mid] >= target) hi = mid; else lo = mid + 1; }
                aux[tid] = lo >> 6;
            }
        }
    }
    gbar(cnt, flag, 1);

    // ===================== phase 1: QKV GEMM (768 virtual blocks) ===========
    for (int vb = bid; vb < 768; vb += NBLK) {
        __syncthreads();
        const int K = DD;
        int m0 = (vb & 31) * 64, n0 = (vb >> 5) * 128;
        int wr = (wave >> 1) * 32, wc = (wave & 1) * 64;
        int srow = wave * 16 + (lane >> 2);
        int scol = (lane & 3) * 8;
        const short* Ag = xo + (size_t)(m0 + srow) * K + scol;
        const short* Bg = wqT + (size_t)(n0 + srow) * K + scol;

#pragma unroll
        for (int ks = 0; ks < 2; ++ks) {
            gload16(Ag + ks * 32, &sh.g.As[0][ks][(wave * 16) * 32]);
            gload16(Bg + ks * 32, &sh.g.Bs[0][ks][(wave * 16) * 32]);
            gload16(Bg + (size_t)64 * K + ks * 32, &sh.g.Bs[0][ks][(64 + wave * 16) * 32]);
        }
        __syncthreads();

        f32x4 acc[2][4] = {};
        int cur = 0;
        for (int k0 = 0; k0 < K; k0 += 64, cur ^= 1) {
            if (k0 + 64 < K) {
#pragma unroll
                for (int ks = 0; ks < 2; ++ks) {
                    gload16(Ag + k0 + 64 + ks * 32, &sh.g.As[cur ^ 1][ks][(wave * 16) * 32]);
                    gload16(Bg + k0 + 64 + ks * 32, &sh.g.Bs[cur ^ 1][ks][(wave * 16) * 32]);
                    gload16(Bg + (size_t)64 * K + k0 + 64 + ks * 32,
                            &sh.g.Bs[cur ^ 1][ks][(64 + wave * 16) * 32]);
                }
            }
#pragma unroll
            for (int ks = 0; ks < 2; ++ks) {
                bf16x8 af[2], bfr[4];
#pragma unroll
                for (int i = 0; i < 2; ++i)
                    af[i]  = *(const bf16x8*)&sh.g.As[cur][ks][(wr + i * 16 + l15) * 32 + quad * 8];
#pragma unroll
                for (int j = 0; j < 4; ++j)
                    bfr[j] = *(const bf16x8*)&sh.g.Bs[cur][ks][(wc + j * 16 + l15) * 32 + quad * 8];
#pragma unroll
                for (int i = 0; i < 2; ++i)
#pragma unroll
                    for (int j = 0; j < 4; ++j)
                        acc[i][j] = mfma16(af[i], bfr[j], acc[i][j]);
            }
            __syncthreads();
        }

        if (n0 < 2048) {
#pragma unroll
            for (int i = 0; i < 2; ++i)
#pragma unroll
                for (int j = 0; j < 4; ++j)
#pragma unroll
                    for (int r = 0; r < 4; ++r) {
                        int row = m0 + wr + i * 16 + quad * 4 + r;
                        int col = n0 + wc + j * 16 + l15;
                        qk[(size_t)row * QKW + col] = f2bf(acc[i][j][r] + b_qkv[col]);
                    }
        } else {
#pragma unroll
            for (int j = 0; j < 4; ++j) {
                int col = n0 + wc + j * 16 + l15;
                float bv = b_qkv[col];
                int eg = col - 2048;
                int hh = eg >> 6, e = eg & 63;
#pragma unroll
                for (int i = 0; i < 2; ++i) {
                    int tb = m0 + wr + i * 16 + quad * 4;
                    short4v pk;
#pragma unroll
                    for (int r = 0; r < 4; ++r) pk[r] = f2bf(acc[i][j][r] + bv);
                    *(short4v*)&vt[(size_t)hh * (DH * TT) + (size_t)e * TT + tb] = pk;
                }
            }
        }
    }
    gbar(cnt, flag, 2);

    // ===================== phase 2: attention (1024 virtual blocks) =========
    for (int vb = bid; vb < 1024; vb += NBLK) {
        __syncthreads();
        int z = vb >> 9;
        int rem = vb & 511;
        int h = rem & 15, tt = rem >> 4;
        int t0 = tt * 64;
        int myt = wave * 16;
        const short* vbase = vt + (size_t)h * (DH * TT);

        if (z == 1) {
            if (tt >= aux[32]) {
                int total = totalp[0];
                int myd = wave * 16;
                short* K0 = sh.a.Kh[0][0];
                short* K1 = sh.a.Kh[0][1];
                bool keep = (seg[t0 + lane] == total);
                const short* src = qk + (size_t)(t0 + lane) * QKW + 1024 + h * DH + myd;
                union { float4 f; short s[8]; } u0, u1;
                u0.f = keep ? *(const float4*)src : make_float4(0.f, 0.f, 0.f, 0.f);
                u1.f = keep ? *(const float4*)(src + 8) : make_float4(0.f, 0.f, 0.f, 0.f);
                short* dst = (lane < 32) ? &K0[lane] : &K1[lane - 32];
#pragma unroll
                for (int i = 0; i < 8; ++i) {
                    dst[(myd + i) * 32] = u0.s[i];
                    dst[(myd + 8 + i) * 32] = u1.s[i];
                }
                bf16x8 a0 = *(const bf16x8*)&K0[(myd + l15) * 32 + quad * 8];
                bf16x8 a1 = *(const bf16x8*)&K1[(myd + l15) * 32 + quad * 8];
                f32x4 acc2[4] = {};
#pragma unroll
                for (int j = 0; j < 4; ++j) {
                    const short* vrow = vbase + (size_t)(j * 16 + l15) * TT + t0 + quad * 8;
                    bf16x8 b0 = *(const bf16x8*)vrow;
                    bf16x8 b1 = *(const bf16x8*)(vrow + 32);
                    acc2[j] = mfma16(a0, b0, acc2[j]);
                    acc2[j] = mfma16(a1, b1, acc2[j]);
                }
                float* oh = nsout + (size_t)h * 4096;
#pragma unroll
                for (int j = 0; j < 4; ++j)
#pragma unroll
                    for (int r = 0; r < 4; ++r)
                        atomicAdd(&oh[(myd + quad * 4 + r) * DH + j * 16 + l15], acc2[j][r]);
            }
            continue;
        }

        int st0 = aux[tt];
        int sr = lane >> 2;
        int ch = lane & 3;
        const short* kg = qk + 1024 + h * DH;

        {
#pragma unroll
            for (int h2 = 0; h2 < 2; ++h2)
                gload16(qk + (size_t)(t0 + myt + sr) * QKW + h * DH + h2 * 32 + ch * 8,
                        &sh.a.Qh[h2][myt * 32]);
            int s0 = st0 * 64;
            gload16(kg + (size_t)(s0 + myt + sr) * QKW + ch * 8,        &sh.a.Kh[0][0][myt * 32]);
            gload16(kg + (size_t)(s0 + myt + sr) * QKW + 32 + ch * 8,   &sh.a.Kh[0][1][myt * 32]);
            gload16(vbase + (size_t)(myt + sr) * TT + s0 + ch * 8,      &sh.a.Vh[0][0][myt * 32]);
            gload16(vbase + (size_t)(myt + sr) * TT + s0 + 32 + ch * 8, &sh.a.Vh[0][1][myt * 32]);
        }
        __syncthreads();

        bf16x8 af[2];
#pragma unroll
        for (int h2 = 0; h2 < 2; ++h2)
            af[h2] = *(const bf16x8*)&sh.a.Qh[h2][(myt + l15) * 32 + quad * 8];

        int t_val = t0 + myt + l15;
        int seg_lane = seg[t_val];

        f32x4 acc2[4] = {};
        if (seg[t0] == 0) {
            const short* sb = stT + (size_t)h * 4096;
#pragma unroll
            for (int j = 0; j < 4; ++j)
#pragma unroll
                for (int h2 = 0; h2 < 2; ++h2) {
                    bf16x8 a = *(const bf16x8*)(sb + (j * 16 + l15) * 64 + h2 * 32 + quad * 8);
                    acc2[j] = mfma16(a, af[h2], acc2[j]);
                }
            if (seg_lane != 0) {
#pragma unroll
                for (int j = 0; j < 4; ++j)
#pragma unroll
                    for (int r = 0; r < 4; ++r) acc2[j][r] = 0.f;
            }
        }

        int p = 0;
        for (int st = st0; st <= tt; ++st, p ^= 1) {
            if (st != st0) __syncthreads();
            if (st + 1 <= tt) {
                int s1 = (st + 1) * 64;
                gload16(kg + (size_t)(s1 + myt + sr) * QKW + ch * 8,        &sh.a.Kh[p ^ 1][0][myt * 32]);
                gload16(kg + (size_t)(s1 + myt + sr) * QKW + 32 + ch * 8,   &sh.a.Kh[p ^ 1][1][myt * 32]);
                gload16(vbase + (size_t)(myt + sr) * TT + s1 + ch * 8,      &sh.a.Vh[p ^ 1][0][myt * 32]);
                gload16(vbase + (size_t)(myt + sr) * TT + s1 + 32 + ch * 8, &sh.a.Vh[p ^ 1][1][myt * 32]);
            }
            int s0 = st * 64;

            f32x4 sacc[4] = {};
#pragma unroll
            for (int j = 0; j < 4; ++j)
#pragma unroll
                for (int h2 = 0; h2 < 2; ++h2) {
                    bf16x8 kb = *(const bf16x8*)&sh.a.Kh[p][h2][(j * 16 + l15) * 32 + quad * 8];
                    sacc[j] = mfma16(kb, af[h2], sacc[j]);
                }
            int4 seg4[4];
#pragma unroll
            for (int j = 0; j < 4; ++j)
                seg4[j] = *(const int4*)&seg[s0 + j * 16 + quad * 4];
#pragma unroll
            for (int j = 0; j < 4; ++j) {
                short4v pk;
#pragma unroll
                for (int r = 0; r < 4; ++r) {
                    int s_val = s0 + j * 16 + quad * 4 + r;
                    int sv = (r == 0) ? seg4[j].x : (r == 1) ? seg4[j].y : (r == 2) ? seg4[j].z : seg4[j].w;
                    bool ok = (sv == seg_lane) && (s_val <= t_val);
                    pk[r] = ok ? f2bf(sacc[j][r]) : (short)0;
                }
                *(short4v*)&sh.a.Ss[(myt + l15) * 72 + j * 16 + quad * 4] = pk;
            }
            bf16x8 sf[2];
#pragma unroll
            for (int h2 = 0; h2 < 2; ++h2)
                sf[h2] = *(const bf16x8*)&sh.a.Ss[(myt + l15) * 72 + h2 * 32 + quad * 8];
#pragma unroll
            for (int j = 0; j < 4; ++j)
#pragma unroll
                for (int h2 = 0; h2 < 2; ++h2) {
                    bf16x8 vb2 = *(const bf16x8*)&sh.a.Vh[p][h2][(j * 16 + l15) * 32 + quad * 8];
                    acc2[j] = mfma16(vb2, sf[h2], acc2[j]);
                }
        }

#pragma unroll
        for (int j = 0; j < 4; ++j) {
            short4v pk;
#pragma unroll
            for (int r = 0; r < 4; ++r) pk[r] = f2bf(acc2[j][r]);
            *(short4v*)&xo[(size_t)t_val * DD + h * DH + j * 16 + quad * 4] = pk;
        }
    }
    gbar(cnt, flag, 3);

    // ===================== phase 3: out-proj GEMM (256 virtual blocks) ======
    if (bid < 256) {
        const int K = DD, N = DD;
        int m0 = (bid & 31) * 64, n0 = (bid >> 5) * 128;
        int wr = (wave >> 1) * 32, wc = (wave & 1) * 64;
        int srow = wave * 16 + (lane >> 2);
        int scol = (lane & 3) * 8;
        const short* Ag = xo + (size_t)(m0 + srow) * K + scol;
        const short* Bg = woT + (size_t)(n0 + srow) * K + scol;

#pragma unroll
        for (int ks = 0; ks < 2; ++ks) {
            gload16(Ag + ks * 32, &sh.g.As[0][ks][(wave * 16) * 32]);
            gload16(Bg + ks * 32, &sh.g.Bs[0][ks][(wave * 16) * 32]);
            gload16(Bg + (size_t)64 * K + ks * 32, &sh.g.Bs[0][ks][(64 + wave * 16) * 32]);
        }
        __syncthreads();

        f32x4 acc[2][4] = {};
        int cur = 0;
        for (int k0 = 0; k0 < K; k0 += 64, cur ^= 1) {
            if (k0 + 64 < K) {
#pragma unroll
                for (int ks = 0; ks < 2; ++ks) {
                    gload16(Ag + k0 + 64 + ks * 32, &sh.g.As[cur ^ 1][ks][(wave * 16) * 32]);
                    gload16(Bg + k0 + 64 + ks * 32, &sh.g.Bs[cur ^ 1][ks][(wave * 16) * 32]);
                    gload16(Bg + (size_t)64 * K + k0 + 64 + ks * 32,
                            &sh.g.Bs[cur ^ 1][ks][(64 + wave * 16) * 32]);
                }
            }
#pragma unroll
            for (int ks = 0; ks < 2; ++ks) {
                bf16x8 af2[2], bfr[4];
#pragma unroll
                for (int i = 0; i < 2; ++i)
                    af2[i] = *(const bf16x8*)&sh.g.As[cur][ks][(wr + i * 16 + l15) * 32 + quad * 8];
#pragma unroll
                for (int j = 0; j < 4; ++j)
                    bfr[j] = *(const bf16x8*)&sh.g.Bs[cur][ks][(wc + j * 16 + l15) * 32 + quad * 8];
#pragma unroll
                for (int i = 0; i < 2; ++i)
#pragma unroll
                    for (int j = 0; j < 4; ++j)
                        acc[i][j] = mfma16(af2[i], bfr[j], acc[i][j]);
            }
            __syncthreads();
        }

#pragma unroll
        for (int i = 0; i < 2; ++i)
#pragma unroll
            for (int j = 0; j < 4; ++j) {
                int col = n0 + wc + j * 16 + l15;
                float bv = b_out[col];
#pragma unroll
                for (int r = 0; r < 4; ++r) {
                    int row = m0 + wr + i * 16 + quad * 4 + r;
                    x_out[(size_t)row * N + col] = acc[i][j][r] + bv;
                }
            }
    }
}

// ---------------------------------------------------------------------------
// Host launcher — memset barrier words + single regular dispatch.
// ---------------------------------------------------------------------------
extern "C" void kernel_launch(void* const* d_in, const int* in_sizes, int n_in,
                              void* d_out, int out_size, void* d_ws, size_t ws_size,
                              hipStream_t stream) {
    const float* state = (const float*)d_in[0];
    const float* x_in  = (const float*)d_in[1];
    const int*   done  = (const int*)d_in[2];
    const float* w_qkv = (const float*)d_in[3];
    const float* b_qkv = (const float*)d_in[4];
    const float* w_out = (const float*)d_in[5];
    const float* b_out = (const float*)d_in[6];

    char* ws = (char*)d_ws;
    int*   seg    = (int*)ws;                         // 8 KB
    int*   totalp = (int*)(ws + 8192);
    int*   aux    = (int*)(ws + 8256);                // 33 ints (ends 8388)
    int*   bar    = (int*)(ws + 8400);                // 8 ints barrier state
    short* wqT    = (short*)(ws + 8448);              // 6 MB   [3072][1024]
    short* woT    = (short*)(ws + 6299904);           // 2 MB   [1024][1024]
    short* stT    = (short*)(ws + 8397056);           // 128 KB [h][e][d]
    short* qk     = (short*)(ws + 8528128);           // 8 MB   [T][2048] (Q|K)
    short* vt     = (short*)(ws + 16916736);          // 4 MB   [h][e][T]
    short* xo     = (short*)(ws + 21111040);          // 4 MB   x_bf then outb

    float* nsout = (float*)d_out;
    float* x_out = (float*)d_out + HH * DH * DH;

    hipMemsetAsync(bar, 0, 32, stream);

    fused_kernel<<<NBLK, 256, 0, stream>>>(
        x_in, w_qkv, w_out, state, done, b_qkv, b_out,
        xo, wqT, woT, stT, qk, vt, nsout, x_out,
        seg, totalp, aux, bar);
}

// Round 10
// 157.865 us; speedup vs baseline: 2.8043x; 2.0847x over previous
//
#include <hip/hip_runtime.h>

#define TT 2048
#define DD 1024
#define HH 16
#define DH 64
#define QKV_N 3072
#define QKW 2048  // qk buffer width (Q cols 0..1023, K cols 1024..2047)

typedef __attribute__((ext_vector_type(8))) short bf16x8;
typedef __attribute__((ext_vector_type(4))) short short4v;
typedef __attribute__((ext_vector_type(4))) float f32x4;

__device__ inline short f2bf(float f) {
    union { float f; unsigned u; } v; v.f = f;
    unsigned r = v.u + 0x7fff + ((v.u >> 16) & 1);  // RNE
    return (short)(r >> 16);
}

__device__ inline f32x4 mfma16(bf16x8 a, bf16x8 b, f32x4 c) {
    return __builtin_amdgcn_mfma_f32_16x16x32_bf16(a, b, c, 0, 0, 0);
}

__device__ __forceinline__ void gload16(const void* g, void* l) {
    __builtin_amdgcn_global_load_lds(
        (const __attribute__((address_space(1))) unsigned int*)g,
        (__attribute__((address_space(3))) unsigned int*)l, 16, 0, 0);
}

__device__ void transpose_tile(const float* __restrict__ in, short* __restrict__ out,
                               int R, int C, int r0, int c0, float (*tile)[65]) {
    int tid = threadIdx.x;
#pragma unroll
    for (int p = 0; p < 4; ++p) {
        int ch = tid + p * 256;
        int r = ch >> 4, c4 = (ch & 15) * 4;
        float4 v = *(const float4*)&in[(size_t)(r0 + r) * C + c0 + c4];
        tile[r][c4] = v.x; tile[r][c4 + 1] = v.y; tile[r][c4 + 2] = v.z; tile[r][c4 + 3] = v.w;
    }
    __syncthreads();
#pragma unroll
    for (int p = 0; p < 2; ++p) {
        int ch = tid + p * 256;
        int c = ch >> 3, r8 = (ch & 7) * 8;
        short tmp[8];
#pragma unroll
        for (int i = 0; i < 8; ++i) tmp[i] = f2bf(tile[r8 + i][c]);
        *(float4*)&out[(size_t)(c0 + c) * R + r0 + r8] = *(float4*)tmp;
    }
}

// ---------------------------------------------------------------------------
// 1. QKV GEMM with fused input-cast + weight-transpose staging.
//    64x128 tiles, BK=64, double-buffered, ONE barrier per k-step.
//    A staged from x (f32, row-major -> cvt), B staged from w_qkv (f32 [K][N]
//    -> coalesced col-reads, cvt, transposed ds_write). blocks 768..783:
//    stT transposes; block 784: done-scan. grid 785.
// ---------------------------------------------------------------------------
__global__ __launch_bounds__(256, 3) void gemm_qkv(const float* __restrict__ x,
                                                   const float* __restrict__ w_qkv,
                                                   const float* __restrict__ state,
                                                   const int* __restrict__ done,
                                                   const float* __restrict__ bias,
                                                   short* __restrict__ qk,
                                                   short* __restrict__ vt,
                                                   short* __restrict__ stT,
                                                   int* __restrict__ seg,
                                                   int* __restrict__ totalp,
                                                   int* __restrict__ aux) {
    union Sh {
        struct { short As[2][2][64 * 32]; short Bs[2][2][128 * 32]; } g;  // 48 KB
        struct { float tile[64][65]; int scanbuf[2561]; } p;
    };
    __shared__ __align__(16) Sh sh;
    int b = blockIdx.x;
    int tid = threadIdx.x;

    if (b >= 768) {
        if (b < 784) {
            int h = b - 768;
            transpose_tile(state + (size_t)h * 4096, stT + (size_t)h * 4096,
                           DH, DH, 0, 0, sh.p.tile);
        } else {
            // ---- done-scan (verbatim from prep) ----
            int* segl = sh.p.scanbuf;
            int* part = sh.p.scanbuf + 2048;
            int* excl = sh.p.scanbuf + 2304;
            int base = tid * 8;
            int local[8];
            int run = 0;
#pragma unroll
            for (int i = 0; i < 8; ++i) { run += (done[base + i] != 0) ? 1 : 0; local[i] = run; }
            part[tid] = run;
            __syncthreads();
            if (tid < 64) {
                int p4[4];
#pragma unroll
                for (int i = 0; i < 4; ++i) p4[i] = part[tid * 4 + i];
                int s = p4[0] + p4[1] + p4[2] + p4[3];
                int v = s;
#pragma unroll
                for (int off = 1; off < 64; off <<= 1) {
                    int u = __shfl_up(v, off);
                    if (tid >= off) v += u;
                }
                int ex = v - s;
#pragma unroll
                for (int i = 0; i < 4; ++i) { excl[tid * 4 + i] = ex; ex += p4[i]; }
                if (tid == 63) { totalp[0] = v; sh.p.scanbuf[2560] = v; }
            }
            __syncthreads();
            int off = excl[tid];
#pragma unroll
            for (int i = 0; i < 8; ++i) {
                int sv = off + local[i];
                seg[base + i] = sv;
                segl[base + i] = sv;
            }
            __syncthreads();
            if (tid < 33) {
                int target = (tid < 32) ? segl[tid * 64] : sh.p.scanbuf[2560];
                int lo = 0, hi = 2047;
                while (lo < hi) { int mid = (lo + hi) >> 1; if (segl[mid] >= target) hi = mid; else lo = mid + 1; }
                aux[tid] = lo >> 6;
            }
        }
        return;
    }

    // ---- qkv GEMM ----
    const int K = DD, NT = 16;
    int wave = tid >> 6, lane = tid & 63;
    int quad = lane >> 4, l15 = lane & 15;
    int m0 = (b & 31) * 64, n0 = (b >> 5) * 128;
    int wr = (wave >> 1) * 32, wc = (wave & 1) * 64;

    // A staging coords: row = tid>>2 (0..63), kc = tid&3 (8 k each)
    int arow = tid >> 2, kc = tid & 3;
    const float* Abase = x + (size_t)(m0 + arow) * K + kc * 8;
    // B staging coords: n = tid&127, kh = tid>>7 (16 k each)
    int bn = tid & 127, kh = tid >> 7;
    const float* Bbase = w_qkv + (size_t)(kh * 16) * QKV_N + n0 + bn;

    float4 areg[2][2];   // [ks][2x float4]
    float  breg[2][16];  // [ks][16]

#define LOADR(t)                                                              \
    {                                                                         \
        _Pragma("unroll")                                                     \
        for (int ks = 0; ks < 2; ++ks) {                                      \
            const float* ap = Abase + (t) * 64 + ks * 32;                     \
            areg[ks][0] = *(const float4*)ap;                                 \
            areg[ks][1] = *(const float4*)(ap + 4);                           \
            const float* bp = Bbase + (size_t)((t) * 64 + ks * 32) * QKV_N;   \
            _Pragma("unroll")                                                 \
            for (int i = 0; i < 16; ++i)                                      \
                breg[ks][i] = bp[(size_t)i * QKV_N];                          \
        }                                                                     \
    }

#define WRITER(buf)                                                           \
    {                                                                         \
        _Pragma("unroll")                                                     \
        for (int ks = 0; ks < 2; ++ks) {                                      \
            short ta[8] = {f2bf(areg[ks][0].x), f2bf(areg[ks][0].y),          \
                           f2bf(areg[ks][0].z), f2bf(areg[ks][0].w),          \
                           f2bf(areg[ks][1].x), f2bf(areg[ks][1].y),          \
                           f2bf(areg[ks][1].z), f2bf(areg[ks][1].w)};         \
            *(float4*)&sh.g.As[buf][ks][arow * 32 + kc * 8] = *(float4*)ta;   \
            short tb[16];                                                     \
            _Pragma("unroll")                                                 \
            for (int i = 0; i < 16; ++i) tb[i] = f2bf(breg[ks][i]);           \
            *(float4*)&sh.g.Bs[buf][ks][bn * 32 + kh * 16]     = ((float4*)tb)[0]; \
            *(float4*)&sh.g.Bs[buf][ks][bn * 32 + kh * 16 + 8] = ((float4*)tb)[1]; \
        }                                                                     \
    }

    LOADR(0);
    WRITER(0);
    LOADR(1);
    __syncthreads();

    f32x4 acc[2][4] = {};
#pragma unroll 1
    for (int t = 0; t < NT; ++t) {
        int cur = t & 1;
#pragma unroll
        for (int ks = 0; ks < 2; ++ks) {
            bf16x8 af[2], bfr[4];
#pragma unroll
            for (int i = 0; i < 2; ++i)
                af[i]  = *(const bf16x8*)&sh.g.As[cur][ks][(wr + i * 16 + l15) * 32 + quad * 8];
#pragma unroll
            for (int j = 0; j < 4; ++j)
                bfr[j] = *(const bf16x8*)&sh.g.Bs[cur][ks][(wc + j * 16 + l15) * 32 + quad * 8];
#pragma unroll
            for (int i = 0; i < 2; ++i)
#pragma unroll
                for (int j = 0; j < 4; ++j)
                    acc[i][j] = mfma16(af[i], bfr[j], acc[i][j]);
        }
        if (t + 1 < NT) WRITER(cur ^ 1);   // regs hold step t+1
        if (t + 2 < NT) LOADR(t + 2);
        __syncthreads();
    }
#undef LOADR
#undef WRITER

    if (n0 < 2048) {
#pragma unroll
        for (int i = 0; i < 2; ++i)
#pragma unroll
            for (int j = 0; j < 4; ++j)
#pragma unroll
                for (int r = 0; r < 4; ++r) {
                    int row = m0 + wr + i * 16 + quad * 4 + r;
                    int col = n0 + wc + j * 16 + l15;
                    qk[(size_t)row * QKW + col] = f2bf(acc[i][j][r] + bias[col]);
                }
    } else {
#pragma unroll
        for (int j = 0; j < 4; ++j) {
            int col = n0 + wc + j * 16 + l15;
            float bv = bias[col];
            int eg = col - 2048;
            int hh = eg >> 6, e = eg & 63;
#pragma unroll
            for (int i = 0; i < 2; ++i) {
                int tb = m0 + wr + i * 16 + quad * 4;
                short4v pk;
#pragma unroll
                for (int r = 0; r < 4; ++r) pk[r] = f2bf(acc[i][j][r] + bv);
                *(short4v*)&vt[(size_t)hh * (DH * TT) + (size_t)e * TT + tb] = pk;
            }
        }
    }
}

// ---------------------------------------------------------------------------
// 2. attention — grid (16, 33). y<32: full serial s-loop attn tile (as R5).
//    y==32: per-head state OWNER block: serial over chunks, no atomics,
//    adds `state` itself when no resets (kills prep's nsout-init).
// ---------------------------------------------------------------------------
__global__ __launch_bounds__(256) void attn_mfma(const short* __restrict__ qk,
                                                 const short* __restrict__ vt,
                                                 const short* __restrict__ stT,
                                                 const float* __restrict__ state,
                                                 const int* __restrict__ seg,
                                                 const int* __restrict__ totalp,
                                                 const int* __restrict__ aux,
                                                 short* __restrict__ outb,
                                                 float* __restrict__ nsout) {
    __shared__ __align__(16) short Qh[2][64 * 32];      // [d-half][t][32]
    __shared__ __align__(16) short Kh[2][2][64 * 32];   // [buf][d-half][s][32]
    __shared__ __align__(16) short Vh[2][2][64 * 32];   // [buf][s-half][e][32]
    __shared__ __align__(16) short Ss[64 * 72];         // [t][s], stride 72

    int h = blockIdx.x, tt = blockIdx.y;
    int tid = threadIdx.x, wave = tid >> 6, lane = tid & 63;
    int quad = lane >> 4, l15 = lane & 15;
    int myt = wave * 16;
    const short* vbase = vt + (size_t)h * (DH * TT);

    if (tt == 32) {
        // ---- state owner: new_state[h] = (total? 0 : state) + k_aft^T v_aft
        int total = totalp[0];
        int ct0 = aux[32];
        int myd = wave * 16;
        short* K0 = Kh[0][0];
        short* K1 = Kh[0][1];
        f32x4 acc2[4] = {};
        for (int ct = ct0; ct < 32; ++ct) {
            int t0c = ct * 64;
            bool keep = (seg[t0c + lane] == total);
            const short* src = qk + (size_t)(t0c + lane) * QKW + 1024 + h * DH + myd;
            union { float4 f; short s[8]; } u0, u1;
            u0.f = keep ? *(const float4*)src : make_float4(0.f, 0.f, 0.f, 0.f);
            u1.f = keep ? *(const float4*)(src + 8) : make_float4(0.f, 0.f, 0.f, 0.f);
            short* dst = (lane < 32) ? &K0[lane] : &K1[lane - 32];
#pragma unroll
            for (int i = 0; i < 8; ++i) {
                dst[(myd + i) * 32] = u0.s[i];
                dst[(myd + 8 + i) * 32] = u1.s[i];
            }
            bf16x8 a0 = *(const bf16x8*)&K0[(myd + l15) * 32 + quad * 8];
            bf16x8 a1 = *(const bf16x8*)&K1[(myd + l15) * 32 + quad * 8];
#pragma unroll
            for (int j = 0; j < 4; ++j) {
                const short* vrow = vbase + (size_t)(j * 16 + l15) * TT + t0c + quad * 8;
                bf16x8 b0 = *(const bf16x8*)vrow;
                bf16x8 b1 = *(const bf16x8*)(vrow + 32);
                acc2[j] = mfma16(a0, b0, acc2[j]);
                acc2[j] = mfma16(a1, b1, acc2[j]);
            }
        }
        bool carry = (total == 0);
        float* oh = nsout + (size_t)h * 4096;
        const float* sh0 = state + (size_t)h * 4096;
#pragma unroll
        for (int j = 0; j < 4; ++j)
#pragma unroll
            for (int r = 0; r < 4; ++r) {
                int idx = (myd + quad * 4 + r) * DH + j * 16 + l15;
                oh[idx] = acc2[j][r] + (carry ? sh0[idx] : 0.f);
            }
        return;
    }

    int t0 = tt * 64;
    int st0 = aux[tt];
    int sr = lane >> 2;
    int ch = lane & 3;
    const short* kg = qk + 1024 + h * DH;

    {
#pragma unroll
        for (int h2 = 0; h2 < 2; ++h2)
            gload16(qk + (size_t)(t0 + myt + sr) * QKW + h * DH + h2 * 32 + ch * 8,
                    &Qh[h2][myt * 32]);
        int s0 = st0 * 64;
        gload16(kg + (size_t)(s0 + myt + sr) * QKW + ch * 8,      &Kh[0][0][myt * 32]);
        gload16(kg + (size_t)(s0 + myt + sr) * QKW + 32 + ch * 8, &Kh[0][1][myt * 32]);
        gload16(vbase + (size_t)(myt + sr) * TT + s0 + ch * 8,    &Vh[0][0][myt * 32]);
        gload16(vbase + (size_t)(myt + sr) * TT + s0 + 32 + ch * 8, &Vh[0][1][myt * 32]);
    }
    __syncthreads();

    bf16x8 af[2];
#pragma unroll
    for (int h2 = 0; h2 < 2; ++h2)
        af[h2] = *(const bf16x8*)&Qh[h2][(myt + l15) * 32 + quad * 8];

    int t_val = t0 + myt + l15;
    int seg_lane = seg[t_val];

    f32x4 acc2[4] = {};
    if (seg[t0] == 0) {
        const short* sb = stT + (size_t)h * 4096;  // [e][d]
#pragma unroll
        for (int j = 0; j < 4; ++j)
#pragma unroll
            for (int h2 = 0; h2 < 2; ++h2) {
                bf16x8 a = *(const bf16x8*)(sb + (j * 16 + l15) * 64 + h2 * 32 + quad * 8);
                acc2[j] = mfma16(a, af[h2], acc2[j]);
            }
        if (seg_lane != 0) {
#pragma unroll
            for (int j = 0; j < 4; ++j)
#pragma unroll
                for (int r = 0; r < 4; ++r) acc2[j][r] = 0.f;
        }
    }

    int p = 0;
    for (int st = st0; st <= tt; ++st, p ^= 1) {
        if (st != st0) __syncthreads();
        if (st + 1 <= tt) {
            int s1 = (st + 1) * 64;
            gload16(kg + (size_t)(s1 + myt + sr) * QKW + ch * 8,        &Kh[p ^ 1][0][myt * 32]);
            gload16(kg + (size_t)(s1 + myt + sr) * QKW + 32 + ch * 8,   &Kh[p ^ 1][1][myt * 32]);
            gload16(vbase + (size_t)(myt + sr) * TT + s1 + ch * 8,      &Vh[p ^ 1][0][myt * 32]);
            gload16(vbase + (size_t)(myt + sr) * TT + s1 + 32 + ch * 8, &Vh[p ^ 1][1][myt * 32]);
        }
        int s0 = st * 64;

        f32x4 sacc[4] = {};
#pragma unroll
        for (int j = 0; j < 4; ++j)
#pragma unroll
            for (int h2 = 0; h2 < 2; ++h2) {
                bf16x8 kb = *(const bf16x8*)&Kh[p][h2][(j * 16 + l15) * 32 + quad * 8];
                sacc[j] = mfma16(kb, af[h2], sacc[j]);
            }
        int4 seg4[4];
#pragma unroll
        for (int j = 0; j < 4; ++j)
            seg4[j] = *(const int4*)&seg[s0 + j * 16 + quad * 4];
#pragma unroll
        for (int j = 0; j < 4; ++j) {
            short4v pk;
#pragma unroll
            for (int r = 0; r < 4; ++r) {
                int s_val = s0 + j * 16 + quad * 4 + r;
                int sv = (r == 0) ? seg4[j].x : (r == 1) ? seg4[j].y : (r == 2) ? seg4[j].z : seg4[j].w;
                bool ok = (sv == seg_lane) && (s_val <= t_val);
                pk[r] = ok ? f2bf(sacc[j][r]) : (short)0;
            }
            *(short4v*)&Ss[(myt + l15) * 72 + j * 16 + quad * 4] = pk;
        }
        bf16x8 sf[2];
#pragma unroll
        for (int h2 = 0; h2 < 2; ++h2)
            sf[h2] = *(const bf16x8*)&Ss[(myt + l15) * 72 + h2 * 32 + quad * 8];
#pragma unroll
        for (int j = 0; j < 4; ++j)
#pragma unroll
            for (int h2 = 0; h2 < 2; ++h2) {
                bf16x8 vb = *(const bf16x8*)&Vh[p][h2][(j * 16 + l15) * 32 + quad * 8];
                acc2[j] = mfma16(vb, sf[h2], acc2[j]);
            }
    }

#pragma unroll
    for (int j = 0; j < 4; ++j) {
        short4v pk;
#pragma unroll
        for (int r = 0; r < 4; ++r) pk[r] = f2bf(acc2[j][r]);
        *(short4v*)&outb[(size_t)t_val * DD + h * DH + j * 16 + quad * 4] = pk;
    }
}

// ---------------------------------------------------------------------------
// 3. out-proj GEMM with fused weight-transpose staging. 64x128 tiles, K=1024.
//    A (outb bf16) via gload16 distance-1 dbuf; B from w_out f32 reg-staged.
//    Writes x_out f32 + bias. grid 32x8.
// ---------------------------------------------------------------------------
__global__ __launch_bounds__(256, 3) void gemm_out(const short* __restrict__ A,
                                                   const float* __restrict__ w_out,
                                                   const float* __restrict__ bias,
                                                   float* __restrict__ x_out) {
    __shared__ __align__(16) short As[2][2][64 * 32];
    __shared__ __align__(16) short Bs[2][2][128 * 32];
    const int K = DD, N = DD, NT = 16;
    int tid = threadIdx.x;
    int wave = tid >> 6, lane = tid & 63;
    int quad = lane >> 4, l15 = lane & 15;
    int m0 = blockIdx.x * 64, n0 = blockIdx.y * 128;
    int wr = (wave >> 1) * 32, wc = (wave & 1) * 64;

    int srow = wave * 16 + (lane >> 2);
    int scol = (lane & 3) * 8;
    const short* Ag = A + (size_t)(m0 + srow) * K + scol;

    int bn = tid & 127, kh = tid >> 7;
    const float* Bbase = w_out + (size_t)(kh * 16) * N + n0 + bn;
    float breg[2][16];

#define LOADB(t)                                                              \
    {                                                                         \
        _Pragma("unroll")                                                     \
        for (int ks = 0; ks < 2; ++ks) {                                      \
            const float* bp = Bbase + (size_t)((t) * 64 + ks * 32) * N;       \
            _Pragma("unroll")                                                 \
            for (int i = 0; i < 16; ++i) breg[ks][i] = bp[(size_t)i * N];     \
        }                                                                     \
    }
#define WRITEB(buf)                                                           \
    {                                                                         \
        _Pragma("unroll")                                                     \
        for (int ks = 0; ks < 2; ++ks) {                                      \
            short tb[16];                                                     \
            _Pragma("unroll")                                                 \
            for (int i = 0; i < 16; ++i) tb[i] = f2bf(breg[ks][i]);           \
            *(float4*)&Bs[buf][ks][bn * 32 + kh * 16]     = ((float4*)tb)[0]; \
            *(float4*)&Bs[buf][ks][bn * 32 + kh * 16 + 8] = ((float4*)tb)[1]; \
        }                                                                     \
    }
#define LOADA(t, buf)                                                         \
    {                                                                         \
        _Pragma("unroll")                                                     \
        for (int ks = 0; ks < 2; ++ks)                                        \
            gload16(Ag + (t) * 64 + ks * 32, &As[buf][ks][(wave * 16) * 32]); \
    }

    LOADB(0);
    WRITEB(0);
    LOADB(1);
    LOADA(0, 0);
    __syncthreads();

    f32x4 acc[2][4] = {};
#pragma unroll 1
    for (int t = 0; t < NT; ++t) {
        int cur = t & 1;
        if (t + 1 < NT) LOADA(t + 1, cur ^ 1);
#pragma unroll
        for (int ks = 0; ks < 2; ++ks) {
            bf16x8 af[2], bfr[4];
#pragma unroll
            for (int i = 0; i < 2; ++i)
                af[i]  = *(const bf16x8*)&As[cur][ks][(wr + i * 16 + l15) * 32 + quad * 8];
#pragma unroll
            for (int j = 0; j < 4; ++j)
                bfr[j] = *(const bf16x8*)&Bs[cur][ks][(wc + j * 16 + l15) * 32 + quad * 8];
#pragma unroll
            for (int i = 0; i < 2; ++i)
#pragma unroll
                for (int j = 0; j < 4; ++j)
                    acc[i][j] = mfma16(af[i], bfr[j], acc[i][j]);
        }
        if (t + 1 < NT) WRITEB(cur ^ 1);
        if (t + 2 < NT) LOADB(t + 2);
        __syncthreads();
    }
#undef LOADB
#undef WRITEB
#undef LOADA

#pragma unroll
    for (int i = 0; i < 2; ++i)
#pragma unroll
        for (int j = 0; j < 4; ++j) {
            int col = n0 + wc + j * 16 + l15;
            float bv = bias[col];
#pragma unroll
            for (int r = 0; r < 4; ++r) {
                int row = m0 + wr + i * 16 + quad * 4 + r;
                x_out[(size_t)row * N + col] = acc[i][j][r] + bv;
            }
        }
}

// ---------------------------------------------------------------------------
// Host launcher — 3 dispatches, no memset.
// ---------------------------------------------------------------------------
extern "C" void kernel_launch(void* const* d_in, const int* in_sizes, int n_in,
                              void* d_out, int out_size, void* d_ws, size_t ws_size,
                              hipStream_t stream) {
    const float* state = (const float*)d_in[0];
    const float* x     = (const float*)d_in[1];
    const int*   done  = (const int*)d_in[2];
    const float* w_qkv = (const float*)d_in[3];
    const float* b_qkv = (const float*)d_in[4];
    const float* w_out = (const float*)d_in[5];
    const float* b_out = (const float*)d_in[6];

    char* ws = (char*)d_ws;
    int*   seg    = (int*)ws;                         // 8 KB
    int*   totalp = (int*)(ws + 8192);
    int*   aux    = (int*)(ws + 8256);                // 33 ints
    short* stT    = (short*)(ws + 8448);              // 128 KB [h][e][d]
    short* qk     = (short*)(ws + 139520);            // 8 MB   [T][2048] (Q|K)
    short* vt     = (short*)(ws + 8528128);           // 4 MB   [h][e][T]
    short* outb   = (short*)(ws + 12722432);          // 4 MB   attn output

    float* new_state_out = (float*)d_out;
    float* x_out         = (float*)d_out + HH * DH * DH;

    gemm_qkv<<<785, 256, 0, stream>>>(x, w_qkv, state, done, b_qkv,
                                      qk, vt, stT, seg, totalp, aux);

    attn_mfma<<<dim3(HH, 33), 256, 0, stream>>>(
        qk, vt, stT, state, seg, totalp, aux, outb, new_state_out);

    gemm_out<<<dim3(TT / 64, DD / 128), 256, 0, stream>>>(
        outb, w_out, b_out, x_out);
}

// Round 11
// 149.157 us; speedup vs baseline: 2.9680x; 1.0584x over previous
//
#include <hip/hip_runtime.h>

#define TT 2048
#define DD 1024
#define HH 16
#define DH 64
#define QKV_N 3072
#define QKW 2048  // qk buffer width (Q cols 0..1023, K cols 1024..2047)

typedef __attribute__((ext_vector_type(8))) short bf16x8;
typedef __attribute__((ext_vector_type(4))) short short4v;
typedef __attribute__((ext_vector_type(4))) float f32x4;

__device__ inline short f2bf(float f) {
    union { float f; unsigned u; } v; v.f = f;
    unsigned r = v.u + 0x7fff + ((v.u >> 16) & 1);  // RNE
    return (short)(r >> 16);
}

__device__ inline f32x4 mfma16(bf16x8 a, bf16x8 b, f32x4 c) {
    return __builtin_amdgcn_mfma_f32_16x16x32_bf16(a, b, c, 0, 0, 0);
}

__device__ __forceinline__ void gload16(const void* g, void* l) {
    __builtin_amdgcn_global_load_lds(
        (const __attribute__((address_space(1))) unsigned int*)g,
        (__attribute__((address_space(3))) unsigned int*)l, 16, 0, 0);
}

// ---------------------------------------------------------------------------
// 1. prep: x cast, weight/state transposes, scan. grid = 2065 blocks.
//    (nsout-init removed: attn's state-owner block handles the carry.)
// ---------------------------------------------------------------------------
__device__ void transpose_tile(const float* __restrict__ in, short* __restrict__ out,
                               int R, int C, int r0, int c0, float (*tile)[65]) {
    int tid = threadIdx.x;
#pragma unroll
    for (int p = 0; p < 4; ++p) {
        int ch = tid + p * 256;
        int r = ch >> 4, c4 = (ch & 15) * 4;
        float4 v = *(const float4*)&in[(size_t)(r0 + r) * C + c0 + c4];
        tile[r][c4] = v.x; tile[r][c4 + 1] = v.y; tile[r][c4 + 2] = v.z; tile[r][c4 + 3] = v.w;
    }
    __syncthreads();
#pragma unroll
    for (int p = 0; p < 2; ++p) {
        int ch = tid + p * 256;
        int c = ch >> 3, r8 = (ch & 7) * 8;
        short tmp[8];
#pragma unroll
        for (int i = 0; i < 8; ++i) tmp[i] = f2bf(tile[r8 + i][c]);
        *(float4*)&out[(size_t)(c0 + c) * R + r0 + r8] = *(float4*)tmp;
    }
}

__global__ __launch_bounds__(256) void prep_kernel(const float* __restrict__ x,
                                                   const float* __restrict__ w_qkv,
                                                   const float* __restrict__ w_out,
                                                   const float* __restrict__ state,
                                                   const int* __restrict__ done,
                                                   short* __restrict__ x_bf,
                                                   short* __restrict__ wqT,
                                                   short* __restrict__ woT,
                                                   short* __restrict__ stT,
                                                   int* __restrict__ seg,
                                                   int* __restrict__ totalp,
                                                   int* __restrict__ aux) {
    __shared__ float tile[64][65];
    __shared__ int scanbuf[2048 + 512 + 1];
    int b = blockIdx.x;
    int tid = threadIdx.x;
    if (b < 1024) {
        int i = (b * 256 + tid) * 8;
        float4 a = *(const float4*)&x[i];
        float4 c = *(const float4*)&x[i + 4];
        short tmp[8] = {f2bf(a.x), f2bf(a.y), f2bf(a.z), f2bf(a.w),
                        f2bf(c.x), f2bf(c.y), f2bf(c.z), f2bf(c.w)};
        *(float4*)&x_bf[i] = *(float4*)tmp;
    } else if (b < 1792) {
        int bb = b - 1024;
        transpose_tile(w_qkv, wqT, DD, QKV_N, (bb & 15) * 64, (bb >> 4) * 64, tile);
    } else if (b < 2048) {
        int bb = b - 1792;
        transpose_tile(w_out, woT, DD, DD, (bb & 15) * 64, (bb >> 4) * 64, tile);
    } else if (b < 2064) {
        int h = b - 2048;
        transpose_tile(state + (size_t)h * 4096, stT + (size_t)h * 4096, DH, DH, 0, 0, tile);
    } else {
        int* segl = scanbuf;
        int* part = scanbuf + 2048;
        int* excl = scanbuf + 2304;
        int base = tid * 8;
        int local[8];
        int run = 0;
#pragma unroll
        for (int i = 0; i < 8; ++i) { run += (done[base + i] != 0) ? 1 : 0; local[i] = run; }
        part[tid] = run;
        __syncthreads();
        if (tid < 64) {
            int p4[4];
#pragma unroll
            for (int i = 0; i < 4; ++i) p4[i] = part[tid * 4 + i];
            int s = p4[0] + p4[1] + p4[2] + p4[3];
            int v = s;
#pragma unroll
            for (int off = 1; off < 64; off <<= 1) {
                int u = __shfl_up(v, off);
                if (tid >= off) v += u;
            }
            int ex = v - s;
#pragma unroll
            for (int i = 0; i < 4; ++i) { excl[tid * 4 + i] = ex; ex += p4[i]; }
            if (tid == 63) { totalp[0] = v; scanbuf[2560] = v; }
        }
        __syncthreads();
        int off = excl[tid];
#pragma unroll
        for (int i = 0; i < 8; ++i) {
            int sv = off + local[i];
            seg[base + i] = sv;
            segl[base + i] = sv;
        }
        __syncthreads();
        if (tid < 33) {
            int target = (tid < 32) ? segl[tid * 64] : scanbuf[2560];
            int lo = 0, hi = 2047;
            while (lo < hi) { int mid = (lo + hi) >> 1; if (segl[mid] >= target) hi = mid; else lo = mid + 1; }
            aux[tid] = lo >> 6;
        }
    }
}

// ---------------------------------------------------------------------------
// 2. QKV GEMM, 64x128 tiles, BK=64, double-buffered. grid 768 (1D).
//    Chunked XCD swizzle: vid=(b%8)*96+b/8 puts each XCD on a contiguous
//    slab of n-panels -> per-XCD working set ~4.8MB (L2-fit) vs ~10MB thrash.
// ---------------------------------------------------------------------------
__global__ __launch_bounds__(256, 3) void gemm_qkv(const short* __restrict__ A,
                                                   const short* __restrict__ BT,
                                                   const float* __restrict__ bias,
                                                   short* __restrict__ qk,
                                                   short* __restrict__ vt) {
    __shared__ __align__(16) short As[2][2][64 * 32];   // [buf][ks][row][32]
    __shared__ __align__(16) short Bs[2][2][128 * 32];
    const int K = DD;
    int tid = threadIdx.x;
    int wave = tid >> 6, lane = tid & 63;
    int quad = lane >> 4, l15 = lane & 15;
    int vid = (blockIdx.x & 7) * 96 + (blockIdx.x >> 3);   // XCD-chunked
    int m0 = (vid & 31) * 64, n0 = (vid >> 5) * 128;
    int wr = (wave >> 1) * 32, wc = (wave & 1) * 64;

    int srow = wave * 16 + (lane >> 2);
    int scol = (lane & 3) * 8;
    const short* Ag = A + (size_t)(m0 + srow) * K + scol;
    const short* Bg = BT + (size_t)(n0 + srow) * K + scol;

    // prologue: stage k0=0 into buf 0
#pragma unroll
    for (int ks = 0; ks < 2; ++ks) {
        gload16(Ag + ks * 32, &As[0][ks][(wave * 16) * 32]);
        gload16(Bg + ks * 32, &Bs[0][ks][(wave * 16) * 32]);
        gload16(Bg + (size_t)64 * K + ks * 32, &Bs[0][ks][(64 + wave * 16) * 32]);
    }
    __syncthreads();

    f32x4 acc[2][4] = {};
    int cur = 0;
    for (int k0 = 0; k0 < K; k0 += 64, cur ^= 1) {
        if (k0 + 64 < K) {
#pragma unroll
            for (int ks = 0; ks < 2; ++ks) {
                gload16(Ag + k0 + 64 + ks * 32, &As[cur ^ 1][ks][(wave * 16) * 32]);
                gload16(Bg + k0 + 64 + ks * 32, &Bs[cur ^ 1][ks][(wave * 16) * 32]);
                gload16(Bg + (size_t)64 * K + k0 + 64 + ks * 32,
                        &Bs[cur ^ 1][ks][(64 + wave * 16) * 32]);
            }
        }
#pragma unroll
        for (int ks = 0; ks < 2; ++ks) {
            bf16x8 af[2], bfr[4];
#pragma unroll
            for (int i = 0; i < 2; ++i)
                af[i]  = *(const bf16x8*)&As[cur][ks][(wr + i * 16 + l15) * 32 + quad * 8];
#pragma unroll
            for (int j = 0; j < 4; ++j)
                bfr[j] = *(const bf16x8*)&Bs[cur][ks][(wc + j * 16 + l15) * 32 + quad * 8];
#pragma unroll
            for (int i = 0; i < 2; ++i)
#pragma unroll
                for (int j = 0; j < 4; ++j)
                    acc[i][j] = mfma16(af[i], bfr[j], acc[i][j]);
        }
        __syncthreads();
    }

    if (n0 < 2048) {
#pragma unroll
        for (int i = 0; i < 2; ++i)
#pragma unroll
            for (int j = 0; j < 4; ++j)
#pragma unroll
                for (int r = 0; r < 4; ++r) {
                    int row = m0 + wr + i * 16 + quad * 4 + r;
                    int col = n0 + wc + j * 16 + l15;
                    qk[(size_t)row * QKW + col] = f2bf(acc[i][j][r] + bias[col]);
                }
    } else {
#pragma unroll
        for (int j = 0; j < 4; ++j) {
            int col = n0 + wc + j * 16 + l15;
            float bv = bias[col];
            int eg = col - 2048;
            int hh = eg >> 6, e = eg & 63;
#pragma unroll
            for (int i = 0; i < 2; ++i) {
                int tb = m0 + wr + i * 16 + quad * 4;
                short4v pk;
#pragma unroll
                for (int r = 0; r < 4; ++r) pk[r] = f2bf(acc[i][j][r] + bv);
                *(short4v*)&vt[(size_t)hh * (DH * TT) + (size_t)e * TT + tb] = pk;
            }
        }
    }
}

// ---------------------------------------------------------------------------
// 3. attention — grid 528 (1D), chunked XCD swizzle: each XCD owns 2 heads
//    (KV working set ~1MB, L2-fit). vid=(b%8)*66+b/8; h=vid/33, tt=vid%33.
//    tt<32: full serial s-loop attn tile. tt==32: per-head state OWNER
//    (serial over chunks, no atomics, adds `state` when no resets).
// ---------------------------------------------------------------------------
__global__ __launch_bounds__(256) void attn_mfma(const short* __restrict__ qk,
                                                 const short* __restrict__ vt,
                                                 const short* __restrict__ stT,
                                                 const float* __restrict__ state,
                                                 const int* __restrict__ seg,
                                                 const int* __restrict__ totalp,
                                                 const int* __restrict__ aux,
                                                 short* __restrict__ outb,
                                                 float* __restrict__ nsout) {
    __shared__ __align__(16) short Qh[2][64 * 32];      // [d-half][t][32]
    __shared__ __align__(16) short Kh[2][2][64 * 32];   // [buf][d-half][s][32]
    __shared__ __align__(16) short Vh[2][2][64 * 32];   // [buf][s-half][e][32]
    __shared__ __align__(16) short Ss[64 * 72];         // [t][s], stride 72

    int vid = (blockIdx.x & 7) * 66 + (blockIdx.x >> 3);  // XCD-chunked
    int h = vid / 33, tt = vid % 33;
    int tid = threadIdx.x, wave = tid >> 6, lane = tid & 63;
    int quad = lane >> 4, l15 = lane & 15;
    int myt = wave * 16;
    const short* vbase = vt + (size_t)h * (DH * TT);

    if (tt == 32) {
        // ---- state owner: new_state[h] = (total? 0 : state) + k_aft^T v_aft
        int total = totalp[0];
        int ct0 = aux[32];
        int myd = wave * 16;
        short* K0 = Kh[0][0];
        short* K1 = Kh[0][1];
        f32x4 acc2[4] = {};
        for (int ct = ct0; ct < 32; ++ct) {
            int t0c = ct * 64;
            bool keep = (seg[t0c + lane] == total);
            const short* src = qk + (size_t)(t0c + lane) * QKW + 1024 + h * DH + myd;
            union { float4 f; short s[8]; } u0, u1;
            u0.f = keep ? *(const float4*)src : make_float4(0.f, 0.f, 0.f, 0.f);
            u1.f = keep ? *(const float4*)(src + 8) : make_float4(0.f, 0.f, 0.f, 0.f);
            short* dst = (lane < 32) ? &K0[lane] : &K1[lane - 32];
#pragma unroll
            for (int i = 0; i < 8; ++i) {
                dst[(myd + i) * 32] = u0.s[i];
                dst[(myd + 8 + i) * 32] = u1.s[i];
            }
            __syncthreads();
            bf16x8 a0 = *(const bf16x8*)&K0[(myd + l15) * 32 + quad * 8];
            bf16x8 a1 = *(const bf16x8*)&K1[(myd + l15) * 32 + quad * 8];
#pragma unroll
            for (int j = 0; j < 4; ++j) {
                const short* vrow = vbase + (size_t)(j * 16 + l15) * TT + t0c + quad * 8;
                bf16x8 b0 = *(const bf16x8*)vrow;
                bf16x8 b1 = *(const bf16x8*)(vrow + 32);
                acc2[j] = mfma16(a0, b0, acc2[j]);
                acc2[j] = mfma16(a1, b1, acc2[j]);
            }
            __syncthreads();
        }
        bool carry = (totalp[0] == 0);
        float* oh = nsout + (size_t)h * 4096;
        const float* sh0 = state + (size_t)h * 4096;
#pragma unroll
        for (int j = 0; j < 4; ++j)
#pragma unroll
            for (int r = 0; r < 4; ++r) {
                int idx = (myd + quad * 4 + r) * DH + j * 16 + l15;
                oh[idx] = acc2[j][r] + (carry ? sh0[idx] : 0.f);
            }
        return;
    }

    int t0 = tt * 64;
    int st0 = aux[tt];
    int sr = lane >> 2;          // staging row within 16
    int ch = lane & 3;           // staging col chunk
    const short* kg = qk + 1024 + h * DH;

    // stage Q (wave-private 16 rows) + first K/V tile into buf 0
    {
#pragma unroll
        for (int h2 = 0; h2 < 2; ++h2)
            gload16(qk + (size_t)(t0 + myt + sr) * QKW + h * DH + h2 * 32 + ch * 8,
                    &Qh[h2][myt * 32]);
        int s0 = st0 * 64;
        gload16(kg + (size_t)(s0 + myt + sr) * QKW + ch * 8,      &Kh[0][0][myt * 32]);
        gload16(kg + (size_t)(s0 + myt + sr) * QKW + 32 + ch * 8, &Kh[0][1][myt * 32]);
        gload16(vbase + (size_t)(myt + sr) * TT + s0 + ch * 8,    &Vh[0][0][myt * 32]);
        gload16(vbase + (size_t)(myt + sr) * TT + s0 + 32 + ch * 8, &Vh[0][1][myt * 32]);
    }
    __syncthreads();

    bf16x8 af[2];
#pragma unroll
    for (int h2 = 0; h2 < 2; ++h2)
        af[h2] = *(const bf16x8*)&Qh[h2][(myt + l15) * 32 + quad * 8];

    int t_val = t0 + myt + l15;
    int seg_lane = seg[t_val];

    f32x4 acc2[4] = {};  // out^T: e=j*16+quad*4+r, t=myt+l15
    if (seg[t0] == 0) {
        const short* sb = stT + (size_t)h * 4096;  // [e][d]
#pragma unroll
        for (int j = 0; j < 4; ++j)
#pragma unroll
            for (int h2 = 0; h2 < 2; ++h2) {
                bf16x8 a = *(const bf16x8*)(sb + (j * 16 + l15) * 64 + h2 * 32 + quad * 8);
                acc2[j] = mfma16(a, af[h2], acc2[j]);
            }
        if (seg_lane != 0) {
#pragma unroll
            for (int j = 0; j < 4; ++j)
#pragma unroll
                for (int r = 0; r < 4; ++r) acc2[j][r] = 0.f;
        }
    }

    int p = 0;
    for (int st = st0; st <= tt; ++st, p ^= 1) {
        if (st != st0) __syncthreads();
        if (st + 1 <= tt) {
            int s1 = (st + 1) * 64;
            gload16(kg + (size_t)(s1 + myt + sr) * QKW + ch * 8,        &Kh[p ^ 1][0][myt * 32]);
            gload16(kg + (size_t)(s1 + myt + sr) * QKW + 32 + ch * 8,   &Kh[p ^ 1][1][myt * 32]);
            gload16(vbase + (size_t)(myt + sr) * TT + s1 + ch * 8,      &Vh[p ^ 1][0][myt * 32]);
            gload16(vbase + (size_t)(myt + sr) * TT + s1 + 32 + ch * 8, &Vh[p ^ 1][1][myt * 32]);
        }
        int s0 = st * 64;

        // S^T = K Q^T : D[s][t], s=j*16+quad*4+r, t=myt+l15
        f32x4 sacc[4] = {};
#pragma unroll
        for (int j = 0; j < 4; ++j)
#pragma unroll
            for (int h2 = 0; h2 < 2; ++h2) {
                bf16x8 kb = *(const bf16x8*)&Kh[p][h2][(j * 16 + l15) * 32 + quad * 8];
                sacc[j] = mfma16(kb, af[h2], sacc[j]);
            }
        // mask + packed b64 stores into Ss[t][s] (wave-private rows)
        int4 seg4[4];
#pragma unroll
        for (int j = 0; j < 4; ++j)
            seg4[j] = *(const int4*)&seg[s0 + j * 16 + quad * 4];
#pragma unroll
        for (int j = 0; j < 4; ++j) {
            short4v pk;
#pragma unroll
            for (int r = 0; r < 4; ++r) {
                int s_val = s0 + j * 16 + quad * 4 + r;
                int sv = (r == 0) ? seg4[j].x : (r == 1) ? seg4[j].y : (r == 2) ? seg4[j].z : seg4[j].w;
                bool ok = (sv == seg_lane) && (s_val <= t_val);
                pk[r] = ok ? f2bf(sacc[j][r]) : (short)0;
            }
            *(short4v*)&Ss[(myt + l15) * 72 + j * 16 + quad * 4] = pk;
        }
        // out^T += V^T S^T
        bf16x8 sf[2];
#pragma unroll
        for (int h2 = 0; h2 < 2; ++h2)
            sf[h2] = *(const bf16x8*)&Ss[(myt + l15) * 72 + h2 * 32 + quad * 8];
#pragma unroll
        for (int j = 0; j < 4; ++j)
#pragma unroll
            for (int h2 = 0; h2 < 2; ++h2) {
                bf16x8 vb = *(const bf16x8*)&Vh[p][h2][(j * 16 + l15) * 32 + quad * 8];
                acc2[j] = mfma16(vb, sf[h2], acc2[j]);
            }
    }

#pragma unroll
    for (int j = 0; j < 4; ++j) {
        short4v pk;
#pragma unroll
        for (int r = 0; r < 4; ++r) pk[r] = f2bf(acc2[j][r]);
        *(short4v*)&outb[(size_t)t_val * DD + h * DH + j * 16 + quad * 4] = pk;
    }
}

// ---------------------------------------------------------------------------
// 4. out-proj GEMM, 64x128 tiles, full K=1024, BK=64 double-buffered.
//    grid 256 (1D), chunked XCD swizzle. Writes x_out f32 + bias.
// ---------------------------------------------------------------------------
__global__ __launch_bounds__(256) void gemm_out(const short* __restrict__ A,
                                                const short* __restrict__ BT,
                                                const float* __restrict__ bias,
                                                float* __restrict__ x_out) {
    __shared__ __align__(16) short As[2][2][64 * 32];
    __shared__ __align__(16) short Bs[2][2][128 * 32];
    const int K = DD, N = DD;
    int tid = threadIdx.x;
    int wave = tid >> 6, lane = tid & 63;
    int quad = lane >> 4, l15 = lane & 15;
    int vid = (blockIdx.x & 7) * 32 + (blockIdx.x >> 3);   // XCD-chunked
    int m0 = (vid & 31) * 64, n0 = (vid >> 5) * 128;
    int wr = (wave >> 1) * 32, wc = (wave & 1) * 64;

    int srow = wave * 16 + (lane >> 2);
    int scol = (lane & 3) * 8;
    const short* Ag = A + (size_t)(m0 + srow) * K + scol;
    const short* Bg = BT + (size_t)(n0 + srow) * K + scol;

    // prologue: stage k0=0 into buf 0
#pragma unroll
    for (int ks = 0; ks < 2; ++ks) {
        gload16(Ag + ks * 32, &As[0][ks][(wave * 16) * 32]);
        gload16(Bg + ks * 32, &Bs[0][ks][(wave * 16) * 32]);
        gload16(Bg + (size_t)64 * K + ks * 32, &Bs[0][ks][(64 + wave * 16) * 32]);
    }
    __syncthreads();

    f32x4 acc[2][4] = {};
    int cur = 0;
    for (int k0 = 0; k0 < K; k0 += 64, cur ^= 1) {
        if (k0 + 64 < K) {
#pragma unroll
            for (int ks = 0; ks < 2; ++ks) {
                gload16(Ag + k0 + 64 + ks * 32, &As[cur ^ 1][ks][(wave * 16) * 32]);
                gload16(Bg + k0 + 64 + ks * 32, &Bs[cur ^ 1][ks][(wave * 16) * 32]);
                gload16(Bg + (size_t)64 * K + k0 + 64 + ks * 32,
                        &Bs[cur ^ 1][ks][(64 + wave * 16) * 32]);
            }
        }
#pragma unroll
        for (int ks = 0; ks < 2; ++ks) {
            bf16x8 af[2], bfr[4];
#pragma unroll
            for (int i = 0; i < 2; ++i)
                af[i]  = *(const bf16x8*)&As[cur][ks][(wr + i * 16 + l15) * 32 + quad * 8];
#pragma unroll
            for (int j = 0; j < 4; ++j)
                bfr[j] = *(const bf16x8*)&Bs[cur][ks][(wc + j * 16 + l15) * 32 + quad * 8];
#pragma unroll
            for (int i = 0; i < 2; ++i)
#pragma unroll
                for (int j = 0; j < 4; ++j)
                    acc[i][j] = mfma16(af[i], bfr[j], acc[i][j]);
        }
        __syncthreads();
    }

#pragma unroll
    for (int i = 0; i < 2; ++i)
#pragma unroll
        for (int j = 0; j < 4; ++j) {
            int col = n0 + wc + j * 16 + l15;
            float bv = bias[col];
#pragma unroll
            for (int r = 0; r < 4; ++r) {
                int row = m0 + wr + i * 16 + quad * 4 + r;
                x_out[(size_t)row * N + col] = acc[i][j][r] + bv;
            }
        }
}

// ---------------------------------------------------------------------------
// Host launcher — 4 dispatches.
// ---------------------------------------------------------------------------
extern "C" void kernel_launch(void* const* d_in, const int* in_sizes, int n_in,
                              void* d_out, int out_size, void* d_ws, size_t ws_size,
                              hipStream_t stream) {
    const float* state = (const float*)d_in[0];
    const float* x     = (const float*)d_in[1];
    const int*   done  = (const int*)d_in[2];
    const float* w_qkv = (const float*)d_in[3];
    const float* b_qkv = (const float*)d_in[4];
    const float* w_out = (const float*)d_in[5];
    const float* b_out = (const float*)d_in[6];

    char* ws = (char*)d_ws;
    int*   seg    = (int*)ws;                         // 8 KB
    int*   totalp = (int*)(ws + 8192);
    int*   aux    = (int*)(ws + 8256);                // 33 ints
    short* wqT    = (short*)(ws + 8448);              // 6 MB   [3072][1024]
    short* woT    = (short*)(ws + 6299904);           // 2 MB   [1024][1024]
    short* stT    = (short*)(ws + 8397056);           // 128 KB [h][e][d]
    short* qk     = (short*)(ws + 8528128);           // 8 MB   [T][2048] (Q|K)
    short* vt     = (short*)(ws + 16916736);          // 4 MB   [h][e][T]
    short* xbf_outb = (short*)(ws + 21111040);        // 4 MB   x_bf then outb

    float* new_state_out = (float*)d_out;
    float* x_out         = (float*)d_out + HH * DH * DH;

    prep_kernel<<<2065, 256, 0, stream>>>(x, w_qkv, w_out, state, done,
                                          xbf_outb, wqT, woT, stT,
                                          seg, totalp, aux);

    gemm_qkv<<<768, 256, 0, stream>>>(xbf_outb, wqT, b_qkv, qk, vt);

    attn_mfma<<<528, 256, 0, stream>>>(
        qk, vt, stT, state, seg, totalp, aux, xbf_outb, new_state_out);

    gemm_out<<<256, 256, 0, stream>>>(xbf_outb, woT, b_out, x_out);
}

// Round 12
// 147.023 us; speedup vs baseline: 3.0111x; 1.0145x over previous
//
#include <hip/hip_runtime.h>

#define TT 2048
#define DD 1024
#define HH 16
#define DH 64
#define QKV_N 3072
#define QKW 2048  // qk buffer width (Q cols 0..1023, K cols 1024..2047)

typedef __attribute__((ext_vector_type(8))) short bf16x8;
typedef __attribute__((ext_vector_type(4))) short short4v;
typedef __attribute__((ext_vector_type(4))) float f32x4;

__device__ inline short f2bf(float f) {
    union { float f; unsigned u; } v; v.f = f;
    unsigned r = v.u + 0x7fff + ((v.u >> 16) & 1);  // RNE
    return (short)(r >> 16);
}

__device__ inline f32x4 mfma16(bf16x8 a, bf16x8 b, f32x4 c) {
    return __builtin_amdgcn_mfma_f32_16x16x32_bf16(a, b, c, 0, 0, 0);
}

__device__ __forceinline__ void gload16(const void* g, void* l) {
    __builtin_amdgcn_global_load_lds(
        (const __attribute__((address_space(1))) unsigned int*)g,
        (__attribute__((address_space(3))) unsigned int*)l, 16, 0, 0);
}

// ---------------------------------------------------------------------------
// 1. prep: x cast, weight/state transposes, new_state init, scan.
//    grid = 2129 blocks.
// ---------------------------------------------------------------------------
__device__ void transpose_tile(const float* __restrict__ in, short* __restrict__ out,
                               int R, int C, int r0, int c0, float (*tile)[65]) {
    int tid = threadIdx.x;
#pragma unroll
    for (int p = 0; p < 4; ++p) {
        int ch = tid + p * 256;
        int r = ch >> 4, c4 = (ch & 15) * 4;
        float4 v = *(const float4*)&in[(size_t)(r0 + r) * C + c0 + c4];
        tile[r][c4] = v.x; tile[r][c4 + 1] = v.y; tile[r][c4 + 2] = v.z; tile[r][c4 + 3] = v.w;
    }
    __syncthreads();
#pragma unroll
    for (int p = 0; p < 2; ++p) {
        int ch = tid + p * 256;
        int c = ch >> 3, r8 = (ch & 7) * 8;
        short tmp[8];
#pragma unroll
        for (int i = 0; i < 8; ++i) tmp[i] = f2bf(tile[r8 + i][c]);
        *(float4*)&out[(size_t)(c0 + c) * R + r0 + r8] = *(float4*)tmp;
    }
}

__global__ __launch_bounds__(256) void prep_kernel(const float* __restrict__ x,
                                                   const float* __restrict__ w_qkv,
                                                   const float* __restrict__ w_out,
                                                   const float* __restrict__ state,
                                                   const int* __restrict__ done,
                                                   short* __restrict__ x_bf,
                                                   short* __restrict__ wqT,
                                                   short* __restrict__ woT,
                                                   short* __restrict__ stT,
                                                   float* __restrict__ stout,
                                                   int* __restrict__ seg,
                                                   int* __restrict__ totalp,
                                                   int* __restrict__ aux) {
    __shared__ float tile[64][65];
    __shared__ int scanbuf[2048 + 512 + 1];
    int b = blockIdx.x;
    int tid = threadIdx.x;
    if (b < 1024) {
        int i = (b * 256 + tid) * 8;
        float4 a = *(const float4*)&x[i];
        float4 c = *(const float4*)&x[i + 4];
        short tmp[8] = {f2bf(a.x), f2bf(a.y), f2bf(a.z), f2bf(a.w),
                        f2bf(c.x), f2bf(c.y), f2bf(c.z), f2bf(c.w)};
        *(float4*)&x_bf[i] = *(float4*)tmp;
    } else if (b < 1792) {
        int bb = b - 1024;
        transpose_tile(w_qkv, wqT, DD, QKV_N, (bb & 15) * 64, (bb >> 4) * 64, tile);
    } else if (b < 2048) {
        int bb = b - 1792;
        transpose_tile(w_out, woT, DD, DD, (bb & 15) * 64, (bb >> 4) * 64, tile);
    } else if (b < 2064) {
        int h = b - 2048;
        transpose_tile(state + (size_t)h * 4096, stT + (size_t)h * 4096, DH, DH, 0, 0, tile);
    } else if (b < 2128) {
        __shared__ int anyf;
        if (tid == 0) anyf = 0;
        __syncthreads();
        int acc = 0;
#pragma unroll
        for (int i = 0; i < 8; ++i) acc |= done[tid * 8 + i];
        if (acc) anyf = 1;
        __syncthreads();
        int f = ((b - 2064) * 256 + tid) * 4;
        float4 v = anyf ? make_float4(0.f, 0.f, 0.f, 0.f) : *(const float4*)&state[f];
        *(float4*)&stout[f] = v;
    } else {
        int* segl = scanbuf;
        int* part = scanbuf + 2048;
        int* excl = scanbuf + 2304;
        int base = tid * 8;
        int local[8];
        int run = 0;
#pragma unroll
        for (int i = 0; i < 8; ++i) { run += (done[base + i] != 0) ? 1 : 0; local[i] = run; }
        part[tid] = run;
        __syncthreads();
        if (tid < 64) {
            int p4[4];
#pragma unroll
            for (int i = 0; i < 4; ++i) p4[i] = part[tid * 4 + i];
            int s = p4[0] + p4[1] + p4[2] + p4[3];
            int v = s;
#pragma unroll
            for (int off = 1; off < 64; off <<= 1) {
                int u = __shfl_up(v, off);
                if (tid >= off) v += u;
            }
            int ex = v - s;
#pragma unroll
            for (int i = 0; i < 4; ++i) { excl[tid * 4 + i] = ex; ex += p4[i]; }
            if (tid == 63) { totalp[0] = v; scanbuf[2560] = v; }
        }
        __syncthreads();
        int off = excl[tid];
#pragma unroll
        for (int i = 0; i < 8; ++i) {
            int sv = off + local[i];
            seg[base + i] = sv;
            segl[base + i] = sv;
        }
        __syncthreads();
        if (tid < 33) {
            int target = (tid < 32) ? segl[tid * 64] : scanbuf[2560];
            int lo = 0, hi = 2047;
            while (lo < hi) { int mid = (lo + hi) >> 1; if (segl[mid] >= target) hi = mid; else lo = mid + 1; }
            aux[tid] = lo >> 6;
        }
    }
}

// ---------------------------------------------------------------------------
// 2. QKV GEMM, 64x128 tiles, BK=64, double-buffered.
//    grid 32x24 = 768 blocks = 3.0 blocks/CU (LDS 48KB, __launch_bounds cap).
// ---------------------------------------------------------------------------
__global__ __launch_bounds__(256, 3) void gemm_qkv(const short* __restrict__ A,
                                                   const short* __restrict__ BT,
                                                   const float* __restrict__ bias,
                                                   short* __restrict__ qk,
                                                   short* __restrict__ vt) {
    __shared__ __align__(16) short As[2][2][64 * 32];   // [buf][ks][row][32]
    __shared__ __align__(16) short Bs[2][2][128 * 32];
    const int K = DD;
    int tid = threadIdx.x;
    int wave = tid >> 6, lane = tid & 63;
    int quad = lane >> 4, l15 = lane & 15;
    int m0 = blockIdx.x * 64, n0 = blockIdx.y * 128;
    int wr = (wave >> 1) * 32, wc = (wave & 1) * 64;

    // staging: lane covers row wave*16 + (lane>>2), cols (lane&3)*8 (+ks*32)
    int srow = wave * 16 + (lane >> 2);
    int scol = (lane & 3) * 8;
    const short* Ag = A + (size_t)(m0 + srow) * K + scol;
    const short* Bg = BT + (size_t)(n0 + srow) * K + scol;

    // prologue: stage k0=0 into buf 0
#pragma unroll
    for (int ks = 0; ks < 2; ++ks) {
        gload16(Ag + ks * 32, &As[0][ks][(wave * 16) * 32]);
        gload16(Bg + ks * 32, &Bs[0][ks][(wave * 16) * 32]);
        gload16(Bg + (size_t)64 * K + ks * 32, &Bs[0][ks][(64 + wave * 16) * 32]);
    }
    __syncthreads();

    f32x4 acc[2][4] = {};
    int cur = 0;
    for (int k0 = 0; k0 < K; k0 += 64, cur ^= 1) {
        if (k0 + 64 < K) {
#pragma unroll
            for (int ks = 0; ks < 2; ++ks) {
                gload16(Ag + k0 + 64 + ks * 32, &As[cur ^ 1][ks][(wave * 16) * 32]);
                gload16(Bg + k0 + 64 + ks * 32, &Bs[cur ^ 1][ks][(wave * 16) * 32]);
                gload16(Bg + (size_t)64 * K + k0 + 64 + ks * 32,
                        &Bs[cur ^ 1][ks][(64 + wave * 16) * 32]);
            }
        }
#pragma unroll
        for (int ks = 0; ks < 2; ++ks) {
            bf16x8 af[2], bfr[4];
#pragma unroll
            for (int i = 0; i < 2; ++i)
                af[i]  = *(const bf16x8*)&As[cur][ks][(wr + i * 16 + l15) * 32 + quad * 8];
#pragma unroll
            for (int j = 0; j < 4; ++j)
                bfr[j] = *(const bf16x8*)&Bs[cur][ks][(wc + j * 16 + l15) * 32 + quad * 8];
#pragma unroll
            for (int i = 0; i < 2; ++i)
#pragma unroll
                for (int j = 0; j < 4; ++j)
                    acc[i][j] = mfma16(af[i], bfr[j], acc[i][j]);
        }
        __syncthreads();
    }

    if (n0 < 2048) {
#pragma unroll
        for (int i = 0; i < 2; ++i)
#pragma unroll
            for (int j = 0; j < 4; ++j)
#pragma unroll
                for (int r = 0; r < 4; ++r) {
                    int row = m0 + wr + i * 16 + quad * 4 + r;
                    int col = n0 + wc + j * 16 + l15;
                    qk[(size_t)row * QKW + col] = f2bf(acc[i][j][r] + bias[col]);
                }
    } else {
#pragma unroll
        for (int j = 0; j < 4; ++j) {
            int col = n0 + wc + j * 16 + l15;
            float bv = bias[col];
            int eg = col - 2048;
            int hh = eg >> 6, e = eg & 63;
#pragma unroll
            for (int i = 0; i < 2; ++i) {
                int tb = m0 + wr + i * 16 + quad * 4;
                short4v pk;
#pragma unroll
                for (int r = 0; r < 4; ++r) pk[r] = f2bf(acc[i][j][r] + bv);
                *(short4v*)&vt[(size_t)hh * (DH * TT) + (size_t)e * TT + tb] = pk;
            }
        }
    }
}

// ---------------------------------------------------------------------------
// 3. attention — full serial s-loop per (h,tt) block: st = aux[tt]..tt,
//    double-buffered K/V staging, direct bf16 output.
//    grid (H, 32, z: 0 attn, 1 state).
// ---------------------------------------------------------------------------
__global__ __launch_bounds__(256) void attn_mfma(const short* __restrict__ qk,
                                                 const short* __restrict__ vt,
                                                 const short* __restrict__ stT,
                                                 const int* __restrict__ seg,
                                                 const int* __restrict__ totalp,
                                                 const int* __restrict__ aux,
                                                 short* __restrict__ outb,
                                                 float* __restrict__ nsout) {
    __shared__ __align__(16) short Qh[2][64 * 32];      // [d-half][t][32]
    __shared__ __align__(16) short Kh[2][2][64 * 32];   // [buf][d-half][s][32]
    __shared__ __align__(16) short Vh[2][2][64 * 32];   // [buf][s-half][e][32]
    __shared__ __align__(16) short Ss[64 * 72];         // [t][s], stride 72

    int h = blockIdx.x, tt = blockIdx.y, z = blockIdx.z;
    int t0 = tt * 64;
    int tid = threadIdx.x, wave = tid >> 6, lane = tid & 63;
    int quad = lane >> 4, l15 = lane & 15;
    int myt = wave * 16;
    const short* vbase = vt + (size_t)h * (DH * TT);

    if (z == 1) {
        // ---- state path: chunk ct = tt; atomicAdd onto prep-initialized nsout
        if (tt < aux[32]) return;
        int total = totalp[0];
        int myd = wave * 16;
        short* K0 = Kh[0][0];
        short* K1 = Kh[0][1];
        bool keep = (seg[t0 + lane] == total);
        const short* src = qk + (size_t)(t0 + lane) * QKW + 1024 + h * DH + myd;
        union { float4 f; short s[8]; } u0, u1;
        u0.f = keep ? *(const float4*)src : make_float4(0.f, 0.f, 0.f, 0.f);
        u1.f = keep ? *(const float4*)(src + 8) : make_float4(0.f, 0.f, 0.f, 0.f);
        short* dst = (lane < 32) ? &K0[lane] : &K1[lane - 32];
#pragma unroll
        for (int i = 0; i < 8; ++i) {
            dst[(myd + i) * 32] = u0.s[i];
            dst[(myd + 8 + i) * 32] = u1.s[i];
        }
        bf16x8 a0 = *(const bf16x8*)&K0[(myd + l15) * 32 + quad * 8];
        bf16x8 a1 = *(const bf16x8*)&K1[(myd + l15) * 32 + quad * 8];
        f32x4 acc2[4] = {};
#pragma unroll
        for (int j = 0; j < 4; ++j) {
            const short* vrow = vbase + (size_t)(j * 16 + l15) * TT + t0 + quad * 8;
            bf16x8 b0 = *(const bf16x8*)vrow;
            bf16x8 b1 = *(const bf16x8*)(vrow + 32);
            acc2[j] = mfma16(a0, b0, acc2[j]);
            acc2[j] = mfma16(a1, b1, acc2[j]);
        }
        float* oh = nsout + (size_t)h * 4096;
#pragma unroll
        for (int j = 0; j < 4; ++j)
#pragma unroll
            for (int r = 0; r < 4; ++r)
                atomicAdd(&oh[(myd + quad * 4 + r) * DH + j * 16 + l15], acc2[j][r]);
        return;
    }

    int st0 = aux[tt];
    int sr = lane >> 2;          // staging row within 16
    int ch = lane & 3;           // staging col chunk
    const short* kg = qk + 1024 + h * DH;

    // stage Q (wave-private 16 rows) + first K/V tile into buf 0
    {
#pragma unroll
        for (int h2 = 0; h2 < 2; ++h2)
            gload16(qk + (size_t)(t0 + myt + sr) * QKW + h * DH + h2 * 32 + ch * 8,
                    &Qh[h2][myt * 32]);
        int s0 = st0 * 64;
        gload16(kg + (size_t)(s0 + myt + sr) * QKW + ch * 8,      &Kh[0][0][myt * 32]);
        gload16(kg + (size_t)(s0 + myt + sr) * QKW + 32 + ch * 8, &Kh[0][1][myt * 32]);
        gload16(vbase + (size_t)(myt + sr) * TT + s0 + ch * 8,    &Vh[0][0][myt * 32]);
        gload16(vbase + (size_t)(myt + sr) * TT + s0 + 32 + ch * 8, &Vh[0][1][myt * 32]);
    }
    __syncthreads();

    bf16x8 af[2];
#pragma unroll
    for (int h2 = 0; h2 < 2; ++h2)
        af[h2] = *(const bf16x8*)&Qh[h2][(myt + l15) * 32 + quad * 8];

    int t_val = t0 + myt + l15;
    int seg_lane = seg[t_val];

    f32x4 acc2[4] = {};  // out^T: e=j*16+quad*4+r, t=myt+l15
    if (seg[t0] == 0) {
        const short* sb = stT + (size_t)h * 4096;  // [e][d]
#pragma unroll
        for (int j = 0; j < 4; ++j)
#pragma unroll
            for (int h2 = 0; h2 < 2; ++h2) {
                bf16x8 a = *(const bf16x8*)(sb + (j * 16 + l15) * 64 + h2 * 32 + quad * 8);
                acc2[j] = mfma16(a, af[h2], acc2[j]);
            }
        if (seg_lane != 0) {
#pragma unroll
            for (int j = 0; j < 4; ++j)
#pragma unroll
                for (int r = 0; r < 4; ++r) acc2[j][r] = 0.f;
        }
    }

    int p = 0;
    for (int st = st0; st <= tt; ++st, p ^= 1) {
        if (st != st0) __syncthreads();
        if (st + 1 <= tt) {
            int s1 = (st + 1) * 64;
            gload16(kg + (size_t)(s1 + myt + sr) * QKW + ch * 8,        &Kh[p ^ 1][0][myt * 32]);
            gload16(kg + (size_t)(s1 + myt + sr) * QKW + 32 + ch * 8,   &Kh[p ^ 1][1][myt * 32]);
            gload16(vbase + (size_t)(myt + sr) * TT + s1 + ch * 8,      &Vh[p ^ 1][0][myt * 32]);
            gload16(vbase + (size_t)(myt + sr) * TT + s1 + 32 + ch * 8, &Vh[p ^ 1][1][myt * 32]);
        }
        int s0 = st * 64;

        // S^T = K Q^T : D[s][t], s=j*16+quad*4+r, t=myt+l15
        f32x4 sacc[4] = {};
#pragma unroll
        for (int j = 0; j < 4; ++j)
#pragma unroll
            for (int h2 = 0; h2 < 2; ++h2) {
                bf16x8 kb = *(const bf16x8*)&Kh[p][h2][(j * 16 + l15) * 32 + quad * 8];
                sacc[j] = mfma16(kb, af[h2], sacc[j]);
            }
        // mask + packed b64 stores into Ss[t][s] (wave-private rows)
        int4 seg4[4];
#pragma unroll
        for (int j = 0; j < 4; ++j)
            seg4[j] = *(const int4*)&seg[s0 + j * 16 + quad * 4];
#pragma unroll
        for (int j = 0; j < 4; ++j) {
            short4v pk;
#pragma unroll
            for (int r = 0; r < 4; ++r) {
                int s_val = s0 + j * 16 + quad * 4 + r;
                int sv = (r == 0) ? seg4[j].x : (r == 1) ? seg4[j].y : (r == 2) ? seg4[j].z : seg4[j].w;
                bool ok = (sv == seg_lane) && (s_val <= t_val);
                pk[r] = ok ? f2bf(sacc[j][r]) : (short)0;
            }
            *(short4v*)&Ss[(myt + l15) * 72 + j * 16 + quad * 4] = pk;
        }
        // out^T += V^T S^T
        bf16x8 sf[2];
#pragma unroll
        for (int h2 = 0; h2 < 2; ++h2)
            sf[h2] = *(const bf16x8*)&Ss[(myt + l15) * 72 + h2 * 32 + quad * 8];
#pragma unroll
        for (int j = 0; j < 4; ++j)
#pragma unroll
            for (int h2 = 0; h2 < 2; ++h2) {
                bf16x8 vb = *(const bf16x8*)&Vh[p][h2][(j * 16 + l15) * 32 + quad * 8];
                acc2[j] = mfma16(vb, sf[h2], acc2[j]);
            }
    }

#pragma unroll
    for (int j = 0; j < 4; ++j) {
        short4v pk;
#pragma unroll
        for (int r = 0; r < 4; ++r) pk[r] = f2bf(acc2[j][r]);
        *(short4v*)&outb[(size_t)t_val * DD + h * DH + j * 16 + quad * 4] = pk;
    }
}

// ---------------------------------------------------------------------------
// 4. out-proj GEMM, 64x128 tiles, full K=1024, BK=64 double-buffered.
//    grid 32x8 = 256 blocks. No split-K, no partials: writes x_out f32 + bias.
// ---------------------------------------------------------------------------
__global__ __launch_bounds__(256) void gemm_out(const short* __restrict__ A,
                                                const short* __restrict__ BT,
                                                const float* __restrict__ bias,
                                                float* __restrict__ x_out) {
    __shared__ __align__(16) short As[2][2][64 * 32];
    __shared__ __align__(16) short Bs[2][2][128 * 32];
    const int K = DD, N = DD;
    int tid = threadIdx.x;
    int wave = tid >> 6, lane = tid & 63;
    int quad = lane >> 4, l15 = lane & 15;
    int m0 = blockIdx.x * 64, n0 = blockIdx.y * 128;
    int wr = (wave >> 1) * 32, wc = (wave & 1) * 64;

    int srow = wave * 16 + (lane >> 2);
    int scol = (lane & 3) * 8;
    const short* Ag = A + (size_t)(m0 + srow) * K + scol;
    const short* Bg = BT + (size_t)(n0 + srow) * K + scol;

    // prologue: stage k0=0 into buf 0
#pragma unroll
    for (int ks = 0; ks < 2; ++ks) {
        gload16(Ag + ks * 32, &As[0][ks][(wave * 16) * 32]);
        gload16(Bg + ks * 32, &Bs[0][ks][(wave * 16) * 32]);
        gload16(Bg + (size_t)64 * K + ks * 32, &Bs[0][ks][(64 + wave * 16) * 32]);
    }
    __syncthreads();

    f32x4 acc[2][4] = {};
    int cur = 0;
    for (int k0 = 0; k0 < K; k0 += 64, cur ^= 1) {
        if (k0 + 64 < K) {
#pragma unroll
            for (int ks = 0; ks < 2; ++ks) {
                gload16(Ag + k0 + 64 + ks * 32, &As[cur ^ 1][ks][(wave * 16) * 32]);
                gload16(Bg + k0 + 64 + ks * 32, &Bs[cur ^ 1][ks][(wave * 16) * 32]);
                gload16(Bg + (size_t)64 * K + k0 + 64 + ks * 32,
                        &Bs[cur ^ 1][ks][(64 + wave * 16) * 32]);
            }
        }
#pragma unroll
        for (int ks = 0; ks < 2; ++ks) {
            bf16x8 af[2], bfr[4];
#pragma unroll
            for (int i = 0; i < 2; ++i)
                af[i]  = *(const bf16x8*)&As[cur][ks][(wr + i * 16 + l15) * 32 + quad * 8];
#pragma unroll
            for (int j = 0; j < 4; ++j)
                bfr[j] = *(const bf16x8*)&Bs[cur][ks][(wc + j * 16 + l15) * 32 + quad * 8];
#pragma unroll
            for (int i = 0; i < 2; ++i)
#pragma unroll
                for (int j = 0; j < 4; ++j)
                    acc[i][j] = mfma16(af[i], bfr[j], acc[i][j]);
        }
        __syncthreads();
    }

#pragma unroll
    for (int i = 0; i < 2; ++i)
#pragma unroll
        for (int j = 0; j < 4; ++j) {
            int col = n0 + wc + j * 16 + l15;
            float bv = bias[col];
#pragma unroll
            for (int r = 0; r < 4; ++r) {
                int row = m0 + wr + i * 16 + quad * 4 + r;
                x_out[(size_t)row * N + col] = acc[i][j][r] + bv;
            }
        }
}

// ---------------------------------------------------------------------------
// Host launcher — 4 dispatches.
// ---------------------------------------------------------------------------
extern "C" void kernel_launch(void* const* d_in, const int* in_sizes, int n_in,
                              void* d_out, int out_size, void* d_ws, size_t ws_size,
                              hipStream_t stream) {
    const float* state = (const float*)d_in[0];
    const float* x     = (const float*)d_in[1];
    const int*   done  = (const int*)d_in[2];
    const float* w_qkv = (const float*)d_in[3];
    const float* b_qkv = (const float*)d_in[4];
    const float* w_out = (const float*)d_in[5];
    const float* b_out = (const float*)d_in[6];

    char* ws = (char*)d_ws;
    int*   seg    = (int*)ws;                         // 8 KB
    int*   totalp = (int*)(ws + 8192);
    int*   aux    = (int*)(ws + 8256);                // 33 ints
    short* wqT    = (short*)(ws + 8448);              // 6 MB   [3072][1024]
    short* woT    = (short*)(ws + 6299904);           // 2 MB   [1024][1024]
    short* stT    = (short*)(ws + 8397056);           // 128 KB [h][e][d]
    short* qk     = (short*)(ws + 8528128);           // 8 MB   [T][2048] (Q|K)
    short* vt     = (short*)(ws + 16916736);          // 4 MB   [h][e][T]
    short* xbf_outb = (short*)(ws + 21111040);        // 4 MB   x_bf then outb

    float* new_state_out = (float*)d_out;
    float* x_out         = (float*)d_out + HH * DH * DH;

    prep_kernel<<<2129, 256, 0, stream>>>(x, w_qkv, w_out, state, done,
                                          xbf_outb, wqT, woT, stT,
                                          new_state_out, seg, totalp, aux);

    gemm_qkv<<<dim3(TT / 64, QKV_N / 128), 256, 0, stream>>>(
        xbf_outb, wqT, b_qkv, qk, vt);

    attn_mfma<<<dim3(HH, TT / 64, 2), 256, 0, stream>>>(
        qk, vt, stT, seg, totalp, aux, xbf_outb, new_state_out);

    gemm_out<<<dim3(TT / 64, DD / 128), 256, 0, stream>>>(
        xbf_outb, woT, b_out, x_out);
}